// Round 11
// baseline (485.744 us; speedup 1.0000x reference)
//
#include <hip/hip_runtime.h>
#include <hip/hip_bf16.h>

// Round 24: gemm_conv v6 — counted-vmcnt 3-buffer pipeline (T4).
// r10 profile: MFMA 22.7% + VALU 13.6% busy, ~64% stall -> the __syncthreads
// vmcnt(0) drain swallowed the prefetch every step. Now: COMPUTE(buf s%3);
// STAGE(tile s+2); s_waitcnt vmcnt(NSEC+1) [all but newest stage in flight];
// raw s_barrier. Loop unrolled x3 (compile-time buffer idx). vmcnt(0) only at
// s=nsteps-2. LDS 3 buffers: conv2 60KB (2 blk/CU), conv1 36KB (4 blk/CU).
// Staging/swizzle/ADV identical to v5 (numerically proven).
// ws layout (floats), total 34,912,000 f = 139.65 MB:
//   yb[0,7077888) t2b[..,28311552) attnb[..,28459008)
//   sc0@28459008 sh0@28459200 sc1@28459392 sh1@28459968 zp@28460544 (256 f)
//   A0 ush @f 28460800 | A1 ush @f 28516096
//   xT ush @f 29013760 | tbT ush @f 30193408
//   pk [33732352, 34912000)

typedef __hip_bfloat16 bf16;
typedef short bf16x8 __attribute__((ext_vector_type(8)));
typedef float f32x4 __attribute__((ext_vector_type(4)));

typedef const __attribute__((address_space(1))) unsigned short* gas_ptr;
typedef __attribute__((address_space(3))) unsigned short* las_ptr;

__device__ __forceinline__ void gload16(const unsigned short* g, unsigned short* l)
{
    __builtin_amdgcn_global_load_lds((gas_ptr)g, (las_ptr)l, 16, 0, 0);
}

__global__ void beacon_kernel(float* out, float val)
{
    out[threadIdx.x] = val;
}

// ------- weight reorder: src f32 [O][C][9] -> dst bf16 [O][tap*C+ci] -------
__global__ __launch_bounds__(256)
void wreorder_kernel(const float* __restrict__ src, unsigned short* __restrict__ dst,
                     int C, int n)
{
    int i = blockIdx.x * 256 + threadIdx.x;
    if (i >= n) return;
    int K = C * 9;
    int o = i / K, r = i % K;
    int tap = r / C, ci = r % C;
    float v = src[(size_t)o * K + ci * 9 + tap];
    bf16 h = __float2bfloat16(v);
    dst[i] = *reinterpret_cast<unsigned short*>(&h);
}

// ---------------- BN scale/shift precompute + zero page (256 f) ------------
__global__ __launch_bounds__(256)
void bnfold_kernel(const float* g0, const float* b0, const float* be0,
                   const float* m0, const float* v0,
                   const float* g1, const float* b1, const float* be1,
                   const float* m1, const float* v1,
                   float* sc0, float* sh0, float* sc1, float* sh1, float* zpf)
{
    int i = blockIdx.x * 256 + threadIdx.x;
    if (i < 192) {
        float s = g0[i] * rsqrtf(v0[i] + 1e-5f);
        sc0[i] = s;
        sh0[i] = (b0[i] - m0[i]) * s + be0[i];
    } else if (i < 768) {
        int c = i - 192;
        float s = g1[c] * rsqrtf(v1[c] + 1e-5f);
        sc1[c] = s;
        sh1[c] = (b1[c] - m1[c]) * s + be1[c];
    } else if (i < 1024) {
        zpf[i - 768] = 0.f;
    }
}

// ------- transpose: x f32 [B][64][9216] -> xT bf16 [B][9216][64] -----------
__global__ __launch_bounds__(256)
void txpose_kernel(const float* __restrict__ src, unsigned short* __restrict__ dst,
                   int C)
{
    __shared__ float tile[64][65];
    const int p0 = blockIdx.x * 64, c0 = blockIdx.y * 64;
    src += (size_t)blockIdx.z * C * 9216;
    dst += (size_t)blockIdx.z * 9216 * C;
    for (int i = threadIdx.x; i < 4096; i += 256) {
        int r = i >> 6, c = i & 63;
        tile[c][r] = src[(size_t)(c0 + r) * 9216 + p0 + c];
    }
    __syncthreads();
    for (int i = threadIdx.x; i < 2048; i += 256) {
        int p = i >> 5, cp = (i & 31) * 2;
        bf16 h0 = __float2bfloat16(tile[p][cp]);
        bf16 h1 = __float2bfloat16(tile[p][cp + 1]);
        unsigned int u = (unsigned int)(*reinterpret_cast<unsigned short*>(&h0))
                       | ((unsigned int)(*reinterpret_cast<unsigned short*>(&h1)) << 16);
        *reinterpret_cast<unsigned int*>(dst + (size_t)(p0 + p) * C + c0 + cp) = u;
    }
}

// ------- fused build_t + transpose -> tbT bf16 [B][9216][192]; grid (144,3,B)
__global__ __launch_bounds__(256)
void build_tT(const float* __restrict__ y, unsigned short* __restrict__ tbT)
{
    __shared__ float tile[64][65];
    const int p0 = blockIdx.x * 64, c0 = blockIdx.y * 64;
    y += (size_t)blockIdx.z * 192 * 9216;
    tbT += (size_t)blockIdx.z * 9216 * 192;
    for (int i = threadIdx.x; i < 4096; i += 256) {
        int r = i >> 6, pcol = i & 63;
        const int c = c0 + r;
        const int pix = p0 + pcol;
        const float* yp = y + (size_t)c * 9216;
        float val;
        if (c0 == 64) {
            val = yp[pix];
        } else {
            const int oh = pix / 96, ow = pix % 96;
            float fh = fminf(fmaxf(oh * 0.5f - 0.25f, 0.f), 47.f);
            float fw = fminf(fmaxf(ow * 0.5f - 0.25f, 0.f), 47.f);
            int hlo = (int)floorf(fh);
            int wlo = (int)floorf(fw);
            int hhi = (hlo < 47) ? hlo + 1 : 47;
            int whi = (wlo < 47) ? wlo + 1 : 47;
            float ff = fh - (float)hlo;
            float fg = fw - (float)wlo;
            int hs[2] = {hlo, hhi}, wss[2] = {wlo, whi};
            float p[2][2];
            for (int a = 0; a < 2; ++a)
                for (int e = 0; e < 2; ++e) {
                    const float* q = yp + (hs[a] * 2) * 96 + wss[e] * 2;
                    float v00 = q[0], v01 = q[1], v10 = q[96], v11 = q[97];
                    p[a][e] = (c0 == 0)
                        ? fmaxf(fmaxf(v00, v01), fmaxf(v10, v11))
                        : 0.25f * (v00 + v01 + v10 + v11);
                }
            val = (p[0][0] * (1.f - ff) + p[1][0] * ff) * (1.f - fg)
                + (p[0][1] * (1.f - ff) + p[1][1] * ff) * fg;
        }
        tile[pcol][r] = val;
    }
    __syncthreads();
    for (int i = threadIdx.x; i < 2048; i += 256) {
        int p = i >> 5, cp = (i & 31) * 2;
        bf16 h0 = __float2bfloat16(tile[p][cp]);
        bf16 h1 = __float2bfloat16(tile[p][cp + 1]);
        unsigned int u = (unsigned int)(*reinterpret_cast<unsigned short*>(&h0))
                       | ((unsigned int)(*reinterpret_cast<unsigned short*>(&h1)) << 16);
        *reinterpret_cast<unsigned int*>(tbT + (size_t)(p0 + p) * 192 + c0 + cp) = u;
    }
}

// ------- implicit-im2col GEMM v6 -------------------------------------------
// out[B][M][9216] = A[M][9C] conv BT[B][9216][C], +BN+ReLU.
// Tile 64M x NT, BK=32, 3-buffer counted-vmcnt pipeline, granule swizzle.
// gridDim = (9216/NT, M/64, B). C%32==0, NT in {128,256}, nsteps%3==0.
template<int C, int NT>
__global__ __launch_bounds__(256)
void gemm_conv(const unsigned short* __restrict__ A,
               const unsigned short* __restrict__ BT,
               const unsigned short* __restrict__ zp,
               const float* __restrict__ sc, const float* __restrict__ sh,
               float* __restrict__ out, int M)
{
    constexpr int K = 9 * C;
    constexpr int nsteps = K / 32;     // 18 or 54, both % 3 == 0
    constexpr int NSEC = NT / 64;      // B sections = B gloads/thread = n-frags
    constexpr int ABUF = 64 * 32;      // 2048 ushorts
    constexpr int BBUF = NT * 32;

    __shared__ __align__(16) unsigned short As[3][ABUF];
    __shared__ __align__(16) unsigned short Bs[3][BBUF];

    const int tid  = threadIdx.x;
    const int w    = tid >> 6;
    const int lane = tid & 63;
    const int l15  = lane & 15, quad = lane >> 4;

    BT  += (size_t)blockIdx.z * 9216 * C;
    out += (size_t)blockIdx.z * (size_t)M * 9216;

    const int row0 = blockIdx.y * 64;
    const int p0   = blockIdx.x * NT;

    f32x4 acc[4][NSEC];
#pragma unroll
    for (int m = 0; m < 4; ++m)
#pragma unroll
        for (int n = 0; n < NSEC; ++n) acc[m][n] = {0.f, 0.f, 0.f, 0.f};

    // staging geometry (v4/v5): row srow, swizzled granule scol in 64B slice
    const int srow = tid >> 2;
    const int scol = (((tid & 3) ^ ((srow >> 1) & 3)) << 3);

    const unsigned short* sA = A + (size_t)(row0 + srow) * K + scol;  // +=32/step

    const unsigned short* bas[NSEC];
    unsigned vm[NSEC];
    {
        int hB[NSEC], wB[NSEC];
#pragma unroll
        for (int r = 0; r < NSEC; ++r) {
            int pB = p0 + 64 * r + srow;
            hB[r] = pB / 96; wB[r] = pB % 96;
            bas[r] = BT + (size_t)pB * C + scol;
            vm[r] = 0u;
        }
#pragma unroll
        for (int tap = 0; tap < 9; ++tap) {
            const int dh = tap / 3 - 1, dw = tap % 3 - 1;
#pragma unroll
            for (int r = 0; r < NSEC; ++r)
                vm[r] |= (unsigned)(((unsigned)(hB[r] + dh) < 96u) &&
                                    ((unsigned)(wB[r] + dw) < 96u)) << tap;
        }
    }

    int tap_s = 0, kk_s = 0;
    int offC_s = -97 * C;                  // pixel offset * C for stage tap
    const unsigned short* sel[NSEC];
#pragma unroll
    for (int r = 0; r < NSEC; ++r)
        sel[r] = (vm[r] & 1u) ? (bas[r] + offC_s) : zp;

    auto STAGE = [&](int bi) {
        gload16(sA, &As[0][0] + bi * ABUF + w * 512);
#pragma unroll
        for (int r = 0; r < NSEC; ++r)
            gload16(sel[r], &Bs[0][0] + bi * BBUF + w * 512 + r * 2048);
    };
    auto ADV = [&]() {
        sA += 32;
        kk_s += 32;
        if (kk_s == C) {
            kk_s = 0; ++tap_s;
            offC_s += ((tap_s == 3) || (tap_s == 6)) ? 94 * C : C;
#pragma unroll
            for (int r = 0; r < NSEC; ++r)
                sel[r] = ((vm[r] >> tap_s) & 1u) ? (bas[r] + offC_s) : zp;
        } else {
#pragma unroll
            for (int r = 0; r < NSEC; ++r)
                sel[r] += 32;
        }
    };

    const int swz8 = (quad ^ ((l15 >> 1) & 3)) * 8;   // read granule (ushorts)

    auto COMPUTE = [&](int bi) {
        const unsigned short* Ab = &As[0][0] + bi * ABUF;
        const unsigned short* Bb = &Bs[0][0] + bi * BBUF;
        bf16x8 a[4], b[NSEC];
#pragma unroll
        for (int m = 0; m < 4; ++m)
            a[m] = *reinterpret_cast<const bf16x8*>(Ab + (m * 16 + l15) * 32 + swz8);
#pragma unroll
        for (int n = 0; n < NSEC; ++n)
            b[n] = *reinterpret_cast<const bf16x8*>(
                Bb + (w * (NT / 4) + n * 16 + l15) * 32 + swz8);
#pragma unroll
        for (int m = 0; m < 4; ++m)
#pragma unroll
            for (int n = 0; n < NSEC; ++n)
                acc[m][n] = __builtin_amdgcn_mfma_f32_16x16x32_bf16(
                    a[m], b[n], acc[m][n], 0, 0, 0);
    };

    // counted wait: all but the newest stage has landed
    auto WAITP = [&]() {
        if constexpr (NSEC == 4) asm volatile("s_waitcnt vmcnt(5)" ::: "memory");
        else                     asm volatile("s_waitcnt vmcnt(3)" ::: "memory");
    };

    // one pipeline iteration: compute tile s from buffer bi, stage tile s+2
    auto ITER = [&](int s, int bi) {
        COMPUTE(bi);
        if (s + 2 < nsteps) { STAGE(bi >= 1 ? bi - 1 : bi + 2); ADV(); }
        if (s < nsteps - 2) {
            WAITP();
            __builtin_amdgcn_s_barrier();
        } else if (s == nsteps - 2) {
            asm volatile("s_waitcnt vmcnt(0)" ::: "memory");
            __builtin_amdgcn_s_barrier();
        }
    };

    STAGE(0); ADV();
    STAGE(1); ADV();
    WAITP();                        // tile 0 landed (tile 1 may be in flight)
    __builtin_amdgcn_s_barrier();

    for (int s = 0; s < nsteps; s += 3) {
        ITER(s + 0, 0);             // stages into buf 2
        ITER(s + 1, 1);             // stages into buf 0
        ITER(s + 2, 2);             // stages into buf 1
    }

#pragma unroll
    for (int m = 0; m < 4; ++m) {
        const int co = row0 + m * 16 + quad * 4;
#pragma unroll
        for (int n = 0; n < NSEC; ++n) {
            const int pix = p0 + w * (NT / 4) + n * 16 + l15;
#pragma unroll
            for (int r = 0; r < 4; ++r) {
                const int c = co + r;
                float v = acc[m][n][r] * sc[c] + sh[c];
                out[(size_t)c * 9216 + pix] = fmaxf(v, 0.f);
            }
        }
    }
}

// ------------- l2norm rows (block per row, shuffle reduce); grid (384,B) ---
__global__ __launch_bounds__(256)
void l2norm_rows(float* __restrict__ t2)
{
    const int c = blockIdx.x;
    float* p = t2 + (size_t)blockIdx.y * 5308416 + (size_t)c * 9216;
    float s = 0.f;
    for (int i = threadIdx.x; i < 9216; i += 256) { float v = p[i]; s += v * v; }
    for (int off = 32; off; off >>= 1) s += __shfl_xor(s, off, 64);
    __shared__ float red[4];
    if ((threadIdx.x & 63) == 0) red[threadIdx.x >> 6] = s;
    __syncthreads();
    float tot = red[0] + red[1] + red[2] + red[3];
    float inv = 1.f / fmaxf(sqrtf(tot), 1e-12f);
    for (int i = threadIdx.x; i < 9216; i += 256) p[i] *= inv;
}

// -------- qk split-K partial: pk[b][z][c][d], 64x64 tile, 4x4/thread -------
__global__ __launch_bounds__(256)
void qk_partial(const float* __restrict__ t2, float* __restrict__ pk)
{
    __shared__ __align__(16) float qs[32][68];
    __shared__ __align__(16) float ks[32][68];
    const int c0 = blockIdx.y * 64, d0 = blockIdx.x * 64;
    const int bz = blockIdx.z, bb = bz >> 3, chunk = bz & 7;
    const int kbase = chunk * 1152;
    const int tid = threadIdx.x, tx = tid & 15, ty = tid >> 4;
    const float* qb = t2 + (size_t)bb * 5308416;
    const float* kb = qb + (size_t)192 * 9216;

    float acc[4][4];
#pragma unroll
    for (int i = 0; i < 4; ++i)
#pragma unroll
        for (int j = 0; j < 4; ++j) acc[i][j] = 0.f;

    for (int n0 = 0; n0 < 1152; n0 += 32) {
        for (int i = tid; i < 512; i += 256) {
            int row = i >> 3, col = (i & 7) * 4;
            f32x4 v = *reinterpret_cast<const f32x4*>(
                qb + (size_t)(c0 + row) * 9216 + kbase + n0 + col);
            qs[col + 0][row] = v[0];
            qs[col + 1][row] = v[1];
            qs[col + 2][row] = v[2];
            qs[col + 3][row] = v[3];
            f32x4 w = *reinterpret_cast<const f32x4*>(
                kb + (size_t)(d0 + row) * 9216 + kbase + n0 + col);
            ks[col + 0][row] = w[0];
            ks[col + 1][row] = w[1];
            ks[col + 2][row] = w[2];
            ks[col + 3][row] = w[3];
        }
        __syncthreads();
#pragma unroll
        for (int kk = 0; kk < 32; ++kk) {
            f32x4 q4 = *reinterpret_cast<const f32x4*>(&qs[kk][ty * 4]);
            f32x4 k4 = *reinterpret_cast<const f32x4*>(&ks[kk][tx * 4]);
#pragma unroll
            for (int i = 0; i < 4; ++i)
#pragma unroll
                for (int j = 0; j < 4; ++j)
                    acc[i][j] += q4[i] * k4[j];
        }
        __syncthreads();
    }

    float* dst = pk + (size_t)bz * 36864;
#pragma unroll
    for (int i = 0; i < 4; ++i)
#pragma unroll
        for (int j = 0; j < 4; ++j)
            dst[(size_t)(c0 + ty * 4 + i) * 192 + d0 + tx * 4 + j] = acc[i][j];
}

// -------- qk reduce: attn[b][i] = temp * sum_z pk[b][z][i]; grid (144,B) ---
__global__ __launch_bounds__(256)
void qk_reduce(const float* __restrict__ pk, const float* __restrict__ temp,
               float* __restrict__ attn)
{
    const int i = blockIdx.x * 256 + threadIdx.x;
    if (i >= 36864) return;
    const int bb = blockIdx.y;
    const float* src = pk + (size_t)bb * 8 * 36864;
    float s = 0.f;
#pragma unroll
    for (int k = 0; k < 8; ++k)
        s += src[(size_t)k * 36864 + i];
    attn[(size_t)bb * 36864 + i] = s * temp[0];
}

// ---------------- softmax over last dim (192); grid (192*B) ----------------
__global__ __launch_bounds__(64)
void softmax192(float* __restrict__ attn)
{
    float* p = attn + (size_t)blockIdx.x * 192;
    const int t = threadIdx.x;
    float e0 = p[t], e1 = p[t + 64], e2 = p[t + 128];
    float m = fmaxf(e0, fmaxf(e1, e2));
    for (int off = 32; off; off >>= 1) m = fmaxf(m, __shfl_xor(m, off, 64));
    e0 = __expf(e0 - m); e1 = __expf(e1 - m); e2 = __expf(e2 - m);
    float s = e0 + e1 + e2;
    for (int off = 32; off; off >>= 1) s += __shfl_xor(s, off, 64);
    float inv = 1.f / s;
    p[t] = e0 * inv; p[t + 64] = e1 * inv; p[t + 128] = e2 * inv;
}

// ------- ao = attn @ v; grid (36, 12, B) -----------------------------------
__global__ __launch_bounds__(256)
void attn_v(const float* __restrict__ attn, const float* __restrict__ t2,
            float* __restrict__ ao)
{
    __shared__ float aL[192 * 16];
    const int c0 = blockIdx.y * 16;
    const int n = blockIdx.x * 256 + threadIdx.x;
    attn += (size_t)blockIdx.z * 36864;
    t2   += (size_t)blockIdx.z * 5308416;
    ao   += (size_t)blockIdx.z * 1769472;
    for (int i = threadIdx.x; i < 3072; i += 256) {
        int d = i >> 4, cc = i & 15;
        aL[d * 16 + cc] = attn[(size_t)(c0 + cc) * 192 + d];
    }
    __syncthreads();
    const float* vb = t2 + (size_t)384 * 9216;
    f32x4 acc[4];
#pragma unroll
    for (int j = 0; j < 4; ++j) acc[j] = {0.f, 0.f, 0.f, 0.f};
    for (int d = 0; d < 192; ++d) {
        float vv = vb[(size_t)d * 9216 + n];
        const f32x4* ap = reinterpret_cast<const f32x4*>(&aL[d * 16]);
#pragma unroll
        for (int j = 0; j < 4; ++j) {
            f32x4 a = ap[j];
            acc[j][0] += a[0] * vv;
            acc[j][1] += a[1] * vv;
            acc[j][2] += a[2] * vv;
            acc[j][3] += a[3] * vv;
        }
    }
#pragma unroll
    for (int j = 0; j < 4; ++j)
#pragma unroll
        for (int r = 0; r < 4; ++r)
            ao[(size_t)(c0 + j * 4 + r) * 9216 + n] = acc[j][r];
}

// ---------------- depthwise 3x3 + bias -> fp32 out; grid (36,192,B) --------
__global__ __launch_bounds__(256)
void dwconv(const float* __restrict__ ao, const float* __restrict__ w2,
            const float* __restrict__ bias2, float* __restrict__ out)
{
    const int c = blockIdx.y;
    const int pix = blockIdx.x * 256 + threadIdx.x;
    const int h = pix / 96, w = pix % 96;
    const float* sp = ao + (size_t)blockIdx.z * 1769472 + (size_t)c * 9216;
    float acc = bias2[c];
#pragma unroll
    for (int kh = 0; kh < 3; ++kh) {
        int hh = h + kh - 1;
        if (hh < 0 || hh >= 96) continue;
#pragma unroll
        for (int kw = 0; kw < 3; ++kw) {
            int ww = w + kw - 1;
            if (ww < 0 || ww >= 96) continue;
            acc += w2[c * 9 + kh * 3 + kw] * sp[hh * 96 + ww];
        }
    }
    out[(size_t)blockIdx.z * 1769472 + (size_t)c * 9216 + pix] = acc;
}

extern "C" void kernel_launch(void* const* d_in, const int* in_sizes, int n_in,
                              void* d_out, int out_size, void* d_ws, size_t ws_size,
                              hipStream_t stream)
{
    float* out = (float*)d_out;

    static const int expected_sizes[16] = {
        2359296, 110592, 192, 192, 192, 192, 192,
        995328, 576, 576, 576, 576, 576, 1, 1728, 192
    };
    if (n_in != 16) {
        beacon_kernel<<<1, 256, 0, stream>>>(out, 100000.f + (float)n_in);
        return;
    }
    for (int i = 0; i < 16; ++i) {
        if (in_sizes[i] != expected_sizes[i]) {
            beacon_kernel<<<1, 256, 0, stream>>>(out, 1000.f * (float)(i + 1));
            return;
        }
    }
    if (out_size != 7077888) {
        beacon_kernel<<<1, 256, 0, stream>>>(out, 50000.f);
        return;
    }
    const size_t needed = (size_t)34912000 * 4;  // 139.65 MB
    if (ws_size < needed) {
        beacon_kernel<<<1, 256, 0, stream>>>(out, 200.f + (float)(ws_size >> 20));
        return;
    }

    const float* x    = (const float*)d_in[0];
    const float* w0   = (const float*)d_in[1];
    const float* b0   = (const float*)d_in[2];
    const float* g0   = (const float*)d_in[3];
    const float* be0  = (const float*)d_in[4];
    const float* m0   = (const float*)d_in[5];
    const float* v0   = (const float*)d_in[6];
    const float* w1   = (const float*)d_in[7];
    const float* b1   = (const float*)d_in[8];
    const float* g1   = (const float*)d_in[9];
    const float* be1  = (const float*)d_in[10];
    const float* m1   = (const float*)d_in[11];
    const float* v1   = (const float*)d_in[12];
    const float* temp = (const float*)d_in[13];
    const float* w2   = (const float*)d_in[14];
    const float* bi2  = (const float*)d_in[15];

    float* ws    = (float*)d_ws;
    float* yb    = ws;                        // 4 x 1,769,472 f
    float* t2b   = ws + 7077888;              // 4 x 5,308,416 f
    float* attnb = ws + 28311552;             // 4 x 36,864 f
    float* sc0   = ws + 28459008;
    float* sh0   = ws + 28459200;
    float* sc1   = ws + 28459392;
    float* sh1   = ws + 28459968;
    float* zpf   = ws + 28460544;             // 256 f zero page
    unsigned short* zp  = (unsigned short*)zpf;
    unsigned short* A0  = (unsigned short*)(ws + 28460800);  // 110,592 bf16
    unsigned short* A1  = (unsigned short*)(ws + 28516096);  // 995,328 bf16
    unsigned short* xT  = (unsigned short*)(ws + 29013760);  // 4 x 9216x64 bf16
    unsigned short* tbT = (unsigned short*)(ws + 30193408);  // 4 x 9216x192 bf16
    float* pk  = ws + 33732352;               // 4 x 8 x 36864 f
    float* aob = yb;  // alias: yb dead after build_tT

    wreorder_kernel<<<dim3(432), dim3(256), 0, stream>>>(w0, A0, 64, 110592);
    wreorder_kernel<<<dim3(3888), dim3(256), 0, stream>>>(w1, A1, 192, 995328);
    bnfold_kernel<<<dim3(4), dim3(256), 0, stream>>>(g0, b0, be0, m0, v0,
                                                     g1, b1, be1, m1, v1,
                                                     sc0, sh0, sc1, sh1, zpf);

    txpose_kernel<<<dim3(144, 1, 4), dim3(256), 0, stream>>>(x, xT, 64);
    gemm_conv<64, 128><<<dim3(72, 3, 4), dim3(256), 0, stream>>>(A0, xT, zp, sc0, sh0, yb, 192);
    build_tT<<<dim3(144, 3, 4), dim3(256), 0, stream>>>(yb, tbT);
    gemm_conv<192, 256><<<dim3(36, 9, 4), dim3(256), 0, stream>>>(A1, tbT, zp, sc1, sh1, t2b, 576);
    l2norm_rows<<<dim3(384, 4), dim3(256), 0, stream>>>(t2b);
    qk_partial<<<dim3(3, 3, 32), dim3(256), 0, stream>>>(t2b, pk);
    qk_reduce<<<dim3(144, 4), dim3(256), 0, stream>>>(pk, temp, attnb);
    softmax192<<<dim3(768), dim3(64), 0, stream>>>(attnb);
    attn_v<<<dim3(36, 12, 4), dim3(256), 0, stream>>>(attnb, t2b, aob);
    dwconv<<<dim3(36, 192, 4), dim3(256), 0, stream>>>(aob, w2, bi2, out);
}

// Round 12
// 461.938 us; speedup vs baseline: 1.0515x; 1.0515x over previous
//
#include <hip/hip_runtime.h>
#include <hip/hip_bf16.h>

// Round 25: (a) XCD-aware bijective block swizzle in gemm_conv — the 9 (conv2)
// / 3 (conv1) M-tiles sharing one B panel now land on the SAME XCD's L2
// (linear dispatch scattered them: stride 36 mod 8 = 4 -> 1.15 GB/dispatch of
// B re-reads served by L3 ~= the 135us wall while MFMA/VALU/LDS/HBM all idle).
// GEMM body = round-10 v5 (proven, 134us). (b) l2norm in-place rewrite deleted:
// rownorms computes inv-norms only; fused qk_softmax applies invq*invk*temp to
// the reduced logits. Launches 13 -> 12.
// ws layout (floats), total 34,913,536 f = 139.65 MB:
//   yb[0,7077888) t2b[..,28311552) attnb[..,28459008)
//   sc0@28459008 sh0@28459200 sc1@28459392 sh1@28459968 zp@28460544 (256 f)
//   A0 ush @f 28460800 | A1 ush @f 28516096
//   xT ush @f 29013760 | tbT ush @f 30193408
//   pk [33732352, 34912000) | rn [34912000, 34913536)

typedef __hip_bfloat16 bf16;
typedef short bf16x8 __attribute__((ext_vector_type(8)));
typedef float f32x4 __attribute__((ext_vector_type(4)));

typedef const __attribute__((address_space(1))) unsigned short* gas_ptr;
typedef __attribute__((address_space(3))) unsigned short* las_ptr;

__device__ __forceinline__ void gload16(const unsigned short* g, unsigned short* l)
{
    __builtin_amdgcn_global_load_lds((gas_ptr)g, (las_ptr)l, 16, 0, 0);
}

__global__ void beacon_kernel(float* out, float val)
{
    out[threadIdx.x] = val;
}

// ------- weight reorder: src f32 [O][C][9] -> dst bf16 [O][tap*C+ci] -------
__global__ __launch_bounds__(256)
void wreorder_kernel(const float* __restrict__ src, unsigned short* __restrict__ dst,
                     int C, int n)
{
    int i = blockIdx.x * 256 + threadIdx.x;
    if (i >= n) return;
    int K = C * 9;
    int o = i / K, r = i % K;
    int tap = r / C, ci = r % C;
    float v = src[(size_t)o * K + ci * 9 + tap];
    bf16 h = __float2bfloat16(v);
    dst[i] = *reinterpret_cast<unsigned short*>(&h);
}

// ---------------- BN scale/shift precompute + zero page (256 f) ------------
__global__ __launch_bounds__(256)
void bnfold_kernel(const float* g0, const float* b0, const float* be0,
                   const float* m0, const float* v0,
                   const float* g1, const float* b1, const float* be1,
                   const float* m1, const float* v1,
                   float* sc0, float* sh0, float* sc1, float* sh1, float* zpf)
{
    int i = blockIdx.x * 256 + threadIdx.x;
    if (i < 192) {
        float s = g0[i] * rsqrtf(v0[i] + 1e-5f);
        sc0[i] = s;
        sh0[i] = (b0[i] - m0[i]) * s + be0[i];
    } else if (i < 768) {
        int c = i - 192;
        float s = g1[c] * rsqrtf(v1[c] + 1e-5f);
        sc1[c] = s;
        sh1[c] = (b1[c] - m1[c]) * s + be1[c];
    } else if (i < 1024) {
        zpf[i - 768] = 0.f;
    }
}

// ------- transpose: x f32 [B][64][9216] -> xT bf16 [B][9216][64] -----------
__global__ __launch_bounds__(256)
void txpose_kernel(const float* __restrict__ src, unsigned short* __restrict__ dst,
                   int C)
{
    __shared__ float tile[64][65];
    const int p0 = blockIdx.x * 64, c0 = blockIdx.y * 64;
    src += (size_t)blockIdx.z * C * 9216;
    dst += (size_t)blockIdx.z * 9216 * C;
    for (int i = threadIdx.x; i < 4096; i += 256) {
        int r = i >> 6, c = i & 63;
        tile[c][r] = src[(size_t)(c0 + r) * 9216 + p0 + c];
    }
    __syncthreads();
    for (int i = threadIdx.x; i < 2048; i += 256) {
        int p = i >> 5, cp = (i & 31) * 2;
        bf16 h0 = __float2bfloat16(tile[p][cp]);
        bf16 h1 = __float2bfloat16(tile[p][cp + 1]);
        unsigned int u = (unsigned int)(*reinterpret_cast<unsigned short*>(&h0))
                       | ((unsigned int)(*reinterpret_cast<unsigned short*>(&h1)) << 16);
        *reinterpret_cast<unsigned int*>(dst + (size_t)(p0 + p) * C + c0 + cp) = u;
    }
}

// ------- fused build_t + transpose -> tbT bf16 [B][9216][192]; grid (144,3,B)
__global__ __launch_bounds__(256)
void build_tT(const float* __restrict__ y, unsigned short* __restrict__ tbT)
{
    __shared__ float tile[64][65];
    const int p0 = blockIdx.x * 64, c0 = blockIdx.y * 64;
    y += (size_t)blockIdx.z * 192 * 9216;
    tbT += (size_t)blockIdx.z * 9216 * 192;
    for (int i = threadIdx.x; i < 4096; i += 256) {
        int r = i >> 6, pcol = i & 63;
        const int c = c0 + r;
        const int pix = p0 + pcol;
        const float* yp = y + (size_t)c * 9216;
        float val;
        if (c0 == 64) {
            val = yp[pix];
        } else {
            const int oh = pix / 96, ow = pix % 96;
            float fh = fminf(fmaxf(oh * 0.5f - 0.25f, 0.f), 47.f);
            float fw = fminf(fmaxf(ow * 0.5f - 0.25f, 0.f), 47.f);
            int hlo = (int)floorf(fh);
            int wlo = (int)floorf(fw);
            int hhi = (hlo < 47) ? hlo + 1 : 47;
            int whi = (wlo < 47) ? wlo + 1 : 47;
            float ff = fh - (float)hlo;
            float fg = fw - (float)wlo;
            int hs[2] = {hlo, hhi}, wss[2] = {wlo, whi};
            float p[2][2];
            for (int a = 0; a < 2; ++a)
                for (int e = 0; e < 2; ++e) {
                    const float* q = yp + (hs[a] * 2) * 96 + wss[e] * 2;
                    float v00 = q[0], v01 = q[1], v10 = q[96], v11 = q[97];
                    p[a][e] = (c0 == 0)
                        ? fmaxf(fmaxf(v00, v01), fmaxf(v10, v11))
                        : 0.25f * (v00 + v01 + v10 + v11);
                }
            val = (p[0][0] * (1.f - ff) + p[1][0] * ff) * (1.f - fg)
                + (p[0][1] * (1.f - ff) + p[1][1] * ff) * fg;
        }
        tile[pcol][r] = val;
    }
    __syncthreads();
    for (int i = threadIdx.x; i < 2048; i += 256) {
        int p = i >> 5, cp = (i & 31) * 2;
        bf16 h0 = __float2bfloat16(tile[p][cp]);
        bf16 h1 = __float2bfloat16(tile[p][cp + 1]);
        unsigned int u = (unsigned int)(*reinterpret_cast<unsigned short*>(&h0))
                       | ((unsigned int)(*reinterpret_cast<unsigned short*>(&h1)) << 16);
        *reinterpret_cast<unsigned int*>(tbT + (size_t)(p0 + p) * 192 + c0 + cp) = u;
    }
}

// ------- implicit-im2col GEMM v7 = v5 body + XCD-aware block swizzle -------
// out[B][M][9216] = A[M][9C] conv BT[B][9216][C], +BN+ReLU.
// Tile 64M x NT, BK=32, dbuf, 1 barrier/step, incremental-pointer staging,
// granule swizzle. Work order y-fastest, chunked per XCD (nwg % 8 == 0) so
// same-B M-tile groups share one XCD's L2.
template<int C, int NT>
__global__ __launch_bounds__(256)
void gemm_conv(const unsigned short* __restrict__ A,
               const unsigned short* __restrict__ BT,
               const unsigned short* __restrict__ zp,
               const float* __restrict__ sc, const float* __restrict__ sh,
               float* __restrict__ out, int M)
{
    constexpr int K = 9 * C;
    constexpr int nsteps = K / 32;     // 18 or 54 (even)
    constexpr int NSEC = NT / 64;      // B sections = gloads/thread = n-frags

    __shared__ __align__(16) unsigned short As[2][64 * 32];   // 2 x 4 KB
    __shared__ __align__(16) unsigned short Bs[2][NT * 32];   // 2 x NT/16 KB

    const int tid  = threadIdx.x;
    const int w    = tid >> 6;
    const int lane = tid & 63;
    const int l15  = lane & 15, quad = lane >> 4;

    // XCD-aware bijective remap: orig -> work id with y fastest, chunked by 8.
    const int GX = gridDim.x, GY = gridDim.y;
    const int nwg = GX * GY * gridDim.z;
    const int orig = blockIdx.x + GX * (blockIdx.y + GY * blockIdx.z);
    const int wk = (orig & 7) * (nwg >> 3) + (orig >> 3);
    const int by = wk % GY;
    const int t2 = wk / GY;
    const int bx = t2 % GX;
    const int bz = t2 / GX;

    BT  += (size_t)bz * 9216 * C;
    out += (size_t)bz * (size_t)M * 9216;

    const int row0 = by * 64;
    const int p0   = bx * NT;

    f32x4 acc[4][NSEC];
#pragma unroll
    for (int m = 0; m < 4; ++m)
#pragma unroll
        for (int n = 0; n < NSEC; ++n) acc[m][n] = {0.f, 0.f, 0.f, 0.f};

    // staging geometry (v4): row srow, swizzled granule scol within 64B slice
    const int srow = tid >> 2;
    const int scol = (((tid & 3) ^ ((srow >> 1) & 3)) << 3);

    const unsigned short* sA = A + (size_t)(row0 + srow) * K + scol;  // +=32/step

    const unsigned short* bas[NSEC];
    unsigned vm[NSEC];
    {
        int hB[NSEC], wB[NSEC];
#pragma unroll
        for (int r = 0; r < NSEC; ++r) {
            int pB = p0 + 64 * r + srow;
            hB[r] = pB / 96; wB[r] = pB % 96;
            bas[r] = BT + (size_t)pB * C + scol;
            vm[r] = 0u;
        }
#pragma unroll
        for (int tap = 0; tap < 9; ++tap) {
            const int dh = tap / 3 - 1, dw = tap % 3 - 1;
#pragma unroll
            for (int r = 0; r < NSEC; ++r)
                vm[r] |= (unsigned)(((unsigned)(hB[r] + dh) < 96u) &&
                                    ((unsigned)(wB[r] + dw) < 96u)) << tap;
        }
    }

    int tap_s = 0, kk_s = 0;
    int offC_s = -97 * C;                  // pixel offset * C for stage tap
    const unsigned short* sel[NSEC];
#pragma unroll
    for (int r = 0; r < NSEC; ++r)
        sel[r] = (vm[r] & 1u) ? (bas[r] + offC_s) : zp;

    auto STAGE = [&](int pb) {
        gload16(sA, &As[0][0] + pb * 2048 + w * 512);
#pragma unroll
        for (int r = 0; r < NSEC; ++r)
            gload16(sel[r], &Bs[0][0] + pb * (NT * 32) + w * 512 + r * 2048);
    };
    auto ADV = [&]() {
        sA += 32;
        kk_s += 32;
        if (kk_s == C) {
            kk_s = 0; ++tap_s;
            offC_s += ((tap_s == 3) || (tap_s == 6)) ? 94 * C : C;
#pragma unroll
            for (int r = 0; r < NSEC; ++r)
                sel[r] = ((vm[r] >> tap_s) & 1u) ? (bas[r] + offC_s) : zp;
        } else {
#pragma unroll
            for (int r = 0; r < NSEC; ++r)
                sel[r] += 32;
        }
    };

    STAGE(0);
    ADV();
    __syncthreads();

    const int swz8 = (quad ^ ((l15 >> 1) & 3)) * 8;   // read granule (ushorts)

    auto COMPUTE = [&](auto pbc) {
        constexpr int PB = decltype(pbc)::value;
        const unsigned short* Ab = &As[0][0] + PB * 2048;
        const unsigned short* Bb = &Bs[0][0] + PB * (NT * 32);
        bf16x8 a[4], b[NSEC];
#pragma unroll
        for (int m = 0; m < 4; ++m)
            a[m] = *reinterpret_cast<const bf16x8*>(Ab + (m * 16 + l15) * 32 + swz8);
#pragma unroll
        for (int n = 0; n < NSEC; ++n)
            b[n] = *reinterpret_cast<const bf16x8*>(
                Bb + (w * (NT / 4) + n * 16 + l15) * 32 + swz8);
#pragma unroll
        for (int m = 0; m < 4; ++m)
#pragma unroll
            for (int n = 0; n < NSEC; ++n)
                acc[m][n] = __builtin_amdgcn_mfma_f32_16x16x32_bf16(
                    a[m], b[n], acc[m][n], 0, 0, 0);
    };

    for (int s = 0; s < nsteps; s += 2) {
        if (s + 1 < nsteps) { STAGE(1); ADV(); }
        COMPUTE(std::integral_constant<int, 0>{});
        __syncthreads();
        if (s + 2 < nsteps) { STAGE(0); ADV(); }
        COMPUTE(std::integral_constant<int, 1>{});
        __syncthreads();
    }

#pragma unroll
    for (int m = 0; m < 4; ++m) {
        const int co = row0 + m * 16 + quad * 4;
#pragma unroll
        for (int n = 0; n < NSEC; ++n) {
            const int pix = p0 + w * (NT / 4) + n * 16 + l15;
#pragma unroll
            for (int r = 0; r < 4; ++r) {
                const int c = co + r;
                float v = acc[m][n][r] * sc[c] + sh[c];
                out[(size_t)c * 9216 + pix] = fmaxf(v, 0.f);
            }
        }
    }
}

// ------- rownorms: inv L2 norm of t2 rows 0..383 (q,k); grid (384,B) -------
__global__ __launch_bounds__(256)
void rownorms(const float* __restrict__ t2, float* __restrict__ rn)
{
    const int c = blockIdx.x;
    const float* p = t2 + (size_t)blockIdx.y * 5308416 + (size_t)c * 9216;
    float s = 0.f;
    for (int i = threadIdx.x; i < 9216; i += 256) { float v = p[i]; s += v * v; }
    for (int off = 32; off; off >>= 1) s += __shfl_xor(s, off, 64);
    __shared__ float red[4];
    if ((threadIdx.x & 63) == 0) red[threadIdx.x >> 6] = s;
    __syncthreads();
    if (threadIdx.x == 0) {
        float tot = red[0] + red[1] + red[2] + red[3];
        rn[(size_t)blockIdx.y * 384 + c] = 1.f / fmaxf(sqrtf(tot), 1e-12f);
    }
}

// -------- qk split-K partial: pk[b][z][c][d], 64x64 tile, 4x4/thread -------
// (reads RAW q,k; normalization applied downstream in qk_softmax)
__global__ __launch_bounds__(256)
void qk_partial(const float* __restrict__ t2, float* __restrict__ pk)
{
    __shared__ __align__(16) float qs[32][68];
    __shared__ __align__(16) float ks[32][68];
    const int c0 = blockIdx.y * 64, d0 = blockIdx.x * 64;
    const int bz = blockIdx.z, bb = bz >> 3, chunk = bz & 7;
    const int kbase = chunk * 1152;
    const int tid = threadIdx.x, tx = tid & 15, ty = tid >> 4;
    const float* qb = t2 + (size_t)bb * 5308416;
    const float* kb = qb + (size_t)192 * 9216;

    float acc[4][4];
#pragma unroll
    for (int i = 0; i < 4; ++i)
#pragma unroll
        for (int j = 0; j < 4; ++j) acc[i][j] = 0.f;

    for (int n0 = 0; n0 < 1152; n0 += 32) {
        for (int i = tid; i < 512; i += 256) {
            int row = i >> 3, col = (i & 7) * 4;
            f32x4 v = *reinterpret_cast<const f32x4*>(
                qb + (size_t)(c0 + row) * 9216 + kbase + n0 + col);
            qs[col + 0][row] = v[0];
            qs[col + 1][row] = v[1];
            qs[col + 2][row] = v[2];
            qs[col + 3][row] = v[3];
            f32x4 w = *reinterpret_cast<const f32x4*>(
                kb + (size_t)(d0 + row) * 9216 + kbase + n0 + col);
            ks[col + 0][row] = w[0];
            ks[col + 1][row] = w[1];
            ks[col + 2][row] = w[2];
            ks[col + 3][row] = w[3];
        }
        __syncthreads();
#pragma unroll
        for (int kk = 0; kk < 32; ++kk) {
            f32x4 q4 = *reinterpret_cast<const f32x4*>(&qs[kk][ty * 4]);
            f32x4 k4 = *reinterpret_cast<const f32x4*>(&ks[kk][tx * 4]);
#pragma unroll
            for (int i = 0; i < 4; ++i)
#pragma unroll
                for (int j = 0; j < 4; ++j)
                    acc[i][j] += q4[i] * k4[j];
        }
        __syncthreads();
    }

    float* dst = pk + (size_t)bz * 36864;
#pragma unroll
    for (int i = 0; i < 4; ++i)
#pragma unroll
        for (int j = 0; j < 4; ++j)
            dst[(size_t)(c0 + ty * 4 + i) * 192 + d0 + tx * 4 + j] = acc[i][j];
}

// -------- fused reduce + scale (invq*invk*temp) + softmax; grid (192,B) ----
__global__ __launch_bounds__(64)
void qk_softmax(const float* __restrict__ pk, const float* __restrict__ rn,
                const float* __restrict__ temp, float* __restrict__ attn)
{
    const int r = blockIdx.x, b = blockIdx.y;
    const int t = threadIdx.x;
    const float* base = pk + (size_t)b * 8 * 36864 + (size_t)r * 192;
    float e0 = 0.f, e1 = 0.f, e2 = 0.f;
#pragma unroll
    for (int z = 0; z < 8; ++z) {
        const float* q = base + (size_t)z * 36864;
        e0 += q[t]; e1 += q[t + 64]; e2 += q[t + 128];
    }
    const float* rb = rn + (size_t)b * 384;
    const float sc = rb[r] * temp[0];
    e0 *= sc * rb[192 + t];
    e1 *= sc * rb[192 + t + 64];
    e2 *= sc * rb[192 + t + 128];
    float m = fmaxf(e0, fmaxf(e1, e2));
    for (int off = 32; off; off >>= 1) m = fmaxf(m, __shfl_xor(m, off, 64));
    e0 = __expf(e0 - m); e1 = __expf(e1 - m); e2 = __expf(e2 - m);
    float s = e0 + e1 + e2;
    for (int off = 32; off; off >>= 1) s += __shfl_xor(s, off, 64);
    float inv = 1.f / s;
    float* p = attn + (size_t)b * 36864 + (size_t)r * 192;
    p[t] = e0 * inv; p[t + 64] = e1 * inv; p[t + 128] = e2 * inv;
}

// ------- ao = attn @ v; grid (36, 12, B) -----------------------------------
__global__ __launch_bounds__(256)
void attn_v(const float* __restrict__ attn, const float* __restrict__ t2,
            float* __restrict__ ao)
{
    __shared__ float aL[192 * 16];
    const int c0 = blockIdx.y * 16;
    const int n = blockIdx.x * 256 + threadIdx.x;
    attn += (size_t)blockIdx.z * 36864;
    t2   += (size_t)blockIdx.z * 5308416;
    ao   += (size_t)blockIdx.z * 1769472;
    for (int i = threadIdx.x; i < 3072; i += 256) {
        int d = i >> 4, cc = i & 15;
        aL[d * 16 + cc] = attn[(size_t)(c0 + cc) * 192 + d];
    }
    __syncthreads();
    const float* vb = t2 + (size_t)384 * 9216;
    f32x4 acc[4];
#pragma unroll
    for (int j = 0; j < 4; ++j) acc[j] = {0.f, 0.f, 0.f, 0.f};
    for (int d = 0; d < 192; ++d) {
        float vv = vb[(size_t)d * 9216 + n];
        const f32x4* ap = reinterpret_cast<const f32x4*>(&aL[d * 16]);
#pragma unroll
        for (int j = 0; j < 4; ++j) {
            f32x4 a = ap[j];
            acc[j][0] += a[0] * vv;
            acc[j][1] += a[1] * vv;
            acc[j][2] += a[2] * vv;
            acc[j][3] += a[3] * vv;
        }
    }
#pragma unroll
    for (int j = 0; j < 4; ++j)
#pragma unroll
        for (int r = 0; r < 4; ++r)
            ao[(size_t)(c0 + j * 4 + r) * 9216 + n] = acc[j][r];
}

// ---------------- depthwise 3x3 + bias -> fp32 out; grid (36,192,B) --------
__global__ __launch_bounds__(256)
void dwconv(const float* __restrict__ ao, const float* __restrict__ w2,
            const float* __restrict__ bias2, float* __restrict__ out)
{
    const int c = blockIdx.y;
    const int pix = blockIdx.x * 256 + threadIdx.x;
    const int h = pix / 96, w = pix % 96;
    const float* sp = ao + (size_t)blockIdx.z * 1769472 + (size_t)c * 9216;
    float acc = bias2[c];
#pragma unroll
    for (int kh = 0; kh < 3; ++kh) {
        int hh = h + kh - 1;
        if (hh < 0 || hh >= 96) continue;
#pragma unroll
        for (int kw = 0; kw < 3; ++kw) {
            int ww = w + kw - 1;
            if (ww < 0 || ww >= 96) continue;
            acc += w2[c * 9 + kh * 3 + kw] * sp[hh * 96 + ww];
        }
    }
    out[(size_t)blockIdx.z * 1769472 + (size_t)c * 9216 + pix] = acc;
}

extern "C" void kernel_launch(void* const* d_in, const int* in_sizes, int n_in,
                              void* d_out, int out_size, void* d_ws, size_t ws_size,
                              hipStream_t stream)
{
    float* out = (float*)d_out;

    static const int expected_sizes[16] = {
        2359296, 110592, 192, 192, 192, 192, 192,
        995328, 576, 576, 576, 576, 576, 1, 1728, 192
    };
    if (n_in != 16) {
        beacon_kernel<<<1, 256, 0, stream>>>(out, 100000.f + (float)n_in);
        return;
    }
    for (int i = 0; i < 16; ++i) {
        if (in_sizes[i] != expected_sizes[i]) {
            beacon_kernel<<<1, 256, 0, stream>>>(out, 1000.f * (float)(i + 1));
            return;
        }
    }
    if (out_size != 7077888) {
        beacon_kernel<<<1, 256, 0, stream>>>(out, 50000.f);
        return;
    }
    const size_t needed = (size_t)34913536 * 4;  // 139.65 MB
    if (ws_size < needed) {
        beacon_kernel<<<1, 256, 0, stream>>>(out, 200.f + (float)(ws_size >> 20));
        return;
    }

    const float* x    = (const float*)d_in[0];
    const float* w0   = (const float*)d_in[1];
    const float* b0   = (const float*)d_in[2];
    const float* g0   = (const float*)d_in[3];
    const float* be0  = (const float*)d_in[4];
    const float* m0   = (const float*)d_in[5];
    const float* v0   = (const float*)d_in[6];
    const float* w1   = (const float*)d_in[7];
    const float* b1   = (const float*)d_in[8];
    const float* g1   = (const float*)d_in[9];
    const float* be1  = (const float*)d_in[10];
    const float* m1   = (const float*)d_in[11];
    const float* v1   = (const float*)d_in[12];
    const float* temp = (const float*)d_in[13];
    const float* w2   = (const float*)d_in[14];
    const float* bi2  = (const float*)d_in[15];

    float* ws    = (float*)d_ws;
    float* yb    = ws;                        // 4 x 1,769,472 f
    float* t2b   = ws + 7077888;              // 4 x 5,308,416 f
    float* attnb = ws + 28311552;             // 4 x 36,864 f
    float* sc0   = ws + 28459008;
    float* sh0   = ws + 28459200;
    float* sc1   = ws + 28459392;
    float* sh1   = ws + 28459968;
    float* zpf   = ws + 28460544;             // 256 f zero page
    unsigned short* zp  = (unsigned short*)zpf;
    unsigned short* A0  = (unsigned short*)(ws + 28460800);  // 110,592 bf16
    unsigned short* A1  = (unsigned short*)(ws + 28516096);  // 995,328 bf16
    unsigned short* xT  = (unsigned short*)(ws + 29013760);  // 4 x 9216x64 bf16
    unsigned short* tbT = (unsigned short*)(ws + 30193408);  // 4 x 9216x192 bf16
    float* pk  = ws + 33732352;               // 4 x 8 x 36864 f
    float* rn  = ws + 34912000;               // 4 x 384 f inv-norms
    float* aob = yb;  // alias: yb dead after build_tT

    wreorder_kernel<<<dim3(432), dim3(256), 0, stream>>>(w0, A0, 64, 110592);
    wreorder_kernel<<<dim3(3888), dim3(256), 0, stream>>>(w1, A1, 192, 995328);
    bnfold_kernel<<<dim3(4), dim3(256), 0, stream>>>(g0, b0, be0, m0, v0,
                                                     g1, b1, be1, m1, v1,
                                                     sc0, sh0, sc1, sh1, zpf);

    txpose_kernel<<<dim3(144, 1, 4), dim3(256), 0, stream>>>(x, xT, 64);
    gemm_conv<64, 128><<<dim3(72, 3, 4), dim3(256), 0, stream>>>(A0, xT, zp, sc0, sh0, yb, 192);
    build_tT<<<dim3(144, 3, 4), dim3(256), 0, stream>>>(yb, tbT);
    gemm_conv<192, 256><<<dim3(36, 9, 4), dim3(256), 0, stream>>>(A1, tbT, zp, sc1, sh1, t2b, 576);
    rownorms<<<dim3(384, 4), dim3(256), 0, stream>>>(t2b, rn);
    qk_partial<<<dim3(3, 3, 32), dim3(256), 0, stream>>>(t2b, pk);
    qk_softmax<<<dim3(192, 4), dim3(64), 0, stream>>>(pk, rn, temp, attnb);
    attn_v<<<dim3(36, 12, 4), dim3(256), 0, stream>>>(attnb, t2b, aob);
    dwconv<<<dim3(36, 192, 4), dim3(256), 0, stream>>>(aob, w2, bi2, out);
}

// Round 13
// 430.278 us; speedup vs baseline: 1.1289x; 1.0736x over previous
//
#include <hip/hip_runtime.h>
#include <hip/hip_bf16.h>

// Round 26: attn@v -> MFMA GEMM.
//  * qk_softmax writes attn as BF16 [192][192] (A-operand layout).
//  * txpose generalized (batch strides); v-section of t2b -> vT bf16
//    [9216][192], ALIASED into tbT's slot (dead after conv2). ws unchanged.
//  * gemm_av: plain 64x256 BK=32 GEMM (v5 staging minus taps/zero-page,
//    granule swizzle, XCD remap), out = aob f32. Replaces attn_v
//    (which re-read the 7.1MB V panel 12x = 340MB L2 traffic + scalar FMA).
// conv2/conv1/qk path otherwise = round 25 (462us, best).
// ws layout (floats), total 34,913,536 f = 139.65 MB:
//   yb[0,7077888) t2b[..,28311552) attnb(ushort)[..,28459008)
//   sc0@28459008 sh0@28459200 sc1@28459392 sh1@28459968 zp@28460544 (256 f)
//   A0 ush @f 28460800 | A1 ush @f 28516096
//   xT ush @f 29013760 | tbT/vT ush @f 30193408
//   pk [33732352, 34912000) | rn [34912000, 34913536)

typedef __hip_bfloat16 bf16;
typedef short bf16x8 __attribute__((ext_vector_type(8)));
typedef float f32x4 __attribute__((ext_vector_type(4)));

typedef const __attribute__((address_space(1))) unsigned short* gas_ptr;
typedef __attribute__((address_space(3))) unsigned short* las_ptr;

__device__ __forceinline__ void gload16(const unsigned short* g, unsigned short* l)
{
    __builtin_amdgcn_global_load_lds((gas_ptr)g, (las_ptr)l, 16, 0, 0);
}

__global__ void beacon_kernel(float* out, float val)
{
    out[threadIdx.x] = val;
}

// ------- weight reorder: src f32 [O][C][9] -> dst bf16 [O][tap*C+ci] -------
__global__ __launch_bounds__(256)
void wreorder_kernel(const float* __restrict__ src, unsigned short* __restrict__ dst,
                     int C, int n)
{
    int i = blockIdx.x * 256 + threadIdx.x;
    if (i >= n) return;
    int K = C * 9;
    int o = i / K, r = i % K;
    int tap = r / C, ci = r % C;
    float v = src[(size_t)o * K + ci * 9 + tap];
    bf16 h = __float2bfloat16(v);
    dst[i] = *reinterpret_cast<unsigned short*>(&h);
}

// ---------------- BN scale/shift precompute + zero page (256 f) ------------
__global__ __launch_bounds__(256)
void bnfold_kernel(const float* g0, const float* b0, const float* be0,
                   const float* m0, const float* v0,
                   const float* g1, const float* b1, const float* be1,
                   const float* m1, const float* v1,
                   float* sc0, float* sh0, float* sc1, float* sh1, float* zpf)
{
    int i = blockIdx.x * 256 + threadIdx.x;
    if (i < 192) {
        float s = g0[i] * rsqrtf(v0[i] + 1e-5f);
        sc0[i] = s;
        sh0[i] = (b0[i] - m0[i]) * s + be0[i];
    } else if (i < 768) {
        int c = i - 192;
        float s = g1[c] * rsqrtf(v1[c] + 1e-5f);
        sc1[c] = s;
        sh1[c] = (b1[c] - m1[c]) * s + be1[c];
    } else if (i < 1024) {
        zpf[i - 768] = 0.f;
    }
}

// ------- transpose: src f32 [C][9216] -> dst bf16 [9216][C]; grid (144,C/64,B)
__global__ __launch_bounds__(256)
void txpose_kernel(const float* __restrict__ src, unsigned short* __restrict__ dst,
                   int C, long sbs, long dbs)
{
    __shared__ float tile[64][65];
    const int p0 = blockIdx.x * 64, c0 = blockIdx.y * 64;
    src += (size_t)blockIdx.z * sbs;
    dst += (size_t)blockIdx.z * dbs;
    for (int i = threadIdx.x; i < 4096; i += 256) {
        int r = i >> 6, c = i & 63;
        tile[c][r] = src[(size_t)(c0 + r) * 9216 + p0 + c];
    }
    __syncthreads();
    for (int i = threadIdx.x; i < 2048; i += 256) {
        int p = i >> 5, cp = (i & 31) * 2;
        bf16 h0 = __float2bfloat16(tile[p][cp]);
        bf16 h1 = __float2bfloat16(tile[p][cp + 1]);
        unsigned int u = (unsigned int)(*reinterpret_cast<unsigned short*>(&h0))
                       | ((unsigned int)(*reinterpret_cast<unsigned short*>(&h1)) << 16);
        *reinterpret_cast<unsigned int*>(dst + (size_t)(p0 + p) * C + c0 + cp) = u;
    }
}

// ------- fused build_t + transpose -> tbT bf16 [B][9216][192]; grid (144,3,B)
__global__ __launch_bounds__(256)
void build_tT(const float* __restrict__ y, unsigned short* __restrict__ tbT)
{
    __shared__ float tile[64][65];
    const int p0 = blockIdx.x * 64, c0 = blockIdx.y * 64;
    y += (size_t)blockIdx.z * 192 * 9216;
    tbT += (size_t)blockIdx.z * 9216 * 192;
    for (int i = threadIdx.x; i < 4096; i += 256) {
        int r = i >> 6, pcol = i & 63;
        const int c = c0 + r;
        const int pix = p0 + pcol;
        const float* yp = y + (size_t)c * 9216;
        float val;
        if (c0 == 64) {
            val = yp[pix];
        } else {
            const int oh = pix / 96, ow = pix % 96;
            float fh = fminf(fmaxf(oh * 0.5f - 0.25f, 0.f), 47.f);
            float fw = fminf(fmaxf(ow * 0.5f - 0.25f, 0.f), 47.f);
            int hlo = (int)floorf(fh);
            int wlo = (int)floorf(fw);
            int hhi = (hlo < 47) ? hlo + 1 : 47;
            int whi = (wlo < 47) ? wlo + 1 : 47;
            float ff = fh - (float)hlo;
            float fg = fw - (float)wlo;
            int hs[2] = {hlo, hhi}, wss[2] = {wlo, whi};
            float p[2][2];
            for (int a = 0; a < 2; ++a)
                for (int e = 0; e < 2; ++e) {
                    const float* q = yp + (hs[a] * 2) * 96 + wss[e] * 2;
                    float v00 = q[0], v01 = q[1], v10 = q[96], v11 = q[97];
                    p[a][e] = (c0 == 0)
                        ? fmaxf(fmaxf(v00, v01), fmaxf(v10, v11))
                        : 0.25f * (v00 + v01 + v10 + v11);
                }
            val = (p[0][0] * (1.f - ff) + p[1][0] * ff) * (1.f - fg)
                + (p[0][1] * (1.f - ff) + p[1][1] * ff) * fg;
        }
        tile[pcol][r] = val;
    }
    __syncthreads();
    for (int i = threadIdx.x; i < 2048; i += 256) {
        int p = i >> 5, cp = (i & 31) * 2;
        bf16 h0 = __float2bfloat16(tile[p][cp]);
        bf16 h1 = __float2bfloat16(tile[p][cp + 1]);
        unsigned int u = (unsigned int)(*reinterpret_cast<unsigned short*>(&h0))
                       | ((unsigned int)(*reinterpret_cast<unsigned short*>(&h1)) << 16);
        *reinterpret_cast<unsigned int*>(tbT + (size_t)(p0 + p) * 192 + c0 + cp) = u;
    }
}

// ------- implicit-im2col GEMM v7 (round-25 body, unchanged) ----------------
template<int C, int NT>
__global__ __launch_bounds__(256)
void gemm_conv(const unsigned short* __restrict__ A,
               const unsigned short* __restrict__ BT,
               const unsigned short* __restrict__ zp,
               const float* __restrict__ sc, const float* __restrict__ sh,
               float* __restrict__ out, int M)
{
    constexpr int K = 9 * C;
    constexpr int nsteps = K / 32;
    constexpr int NSEC = NT / 64;

    __shared__ __align__(16) unsigned short As[2][64 * 32];
    __shared__ __align__(16) unsigned short Bs[2][NT * 32];

    const int tid  = threadIdx.x;
    const int w    = tid >> 6;
    const int lane = tid & 63;
    const int l15  = lane & 15, quad = lane >> 4;

    const int GX = gridDim.x, GY = gridDim.y;
    const int nwg = GX * GY * gridDim.z;
    const int orig = blockIdx.x + GX * (blockIdx.y + GY * blockIdx.z);
    const int wk = (orig & 7) * (nwg >> 3) + (orig >> 3);
    const int by = wk % GY;
    const int t2 = wk / GY;
    const int bx = t2 % GX;
    const int bz = t2 / GX;

    BT  += (size_t)bz * 9216 * C;
    out += (size_t)bz * (size_t)M * 9216;

    const int row0 = by * 64;
    const int p0   = bx * NT;

    f32x4 acc[4][NSEC];
#pragma unroll
    for (int m = 0; m < 4; ++m)
#pragma unroll
        for (int n = 0; n < NSEC; ++n) acc[m][n] = {0.f, 0.f, 0.f, 0.f};

    const int srow = tid >> 2;
    const int scol = (((tid & 3) ^ ((srow >> 1) & 3)) << 3);

    const unsigned short* sA = A + (size_t)(row0 + srow) * K + scol;

    const unsigned short* bas[NSEC];
    unsigned vm[NSEC];
    {
        int hB[NSEC], wB[NSEC];
#pragma unroll
        for (int r = 0; r < NSEC; ++r) {
            int pB = p0 + 64 * r + srow;
            hB[r] = pB / 96; wB[r] = pB % 96;
            bas[r] = BT + (size_t)pB * C + scol;
            vm[r] = 0u;
        }
#pragma unroll
        for (int tap = 0; tap < 9; ++tap) {
            const int dh = tap / 3 - 1, dw = tap % 3 - 1;
#pragma unroll
            for (int r = 0; r < NSEC; ++r)
                vm[r] |= (unsigned)(((unsigned)(hB[r] + dh) < 96u) &&
                                    ((unsigned)(wB[r] + dw) < 96u)) << tap;
        }
    }

    int tap_s = 0, kk_s = 0;
    int offC_s = -97 * C;
    const unsigned short* sel[NSEC];
#pragma unroll
    for (int r = 0; r < NSEC; ++r)
        sel[r] = (vm[r] & 1u) ? (bas[r] + offC_s) : zp;

    auto STAGE = [&](int pb) {
        gload16(sA, &As[0][0] + pb * 2048 + w * 512);
#pragma unroll
        for (int r = 0; r < NSEC; ++r)
            gload16(sel[r], &Bs[0][0] + pb * (NT * 32) + w * 512 + r * 2048);
    };
    auto ADV = [&]() {
        sA += 32;
        kk_s += 32;
        if (kk_s == C) {
            kk_s = 0; ++tap_s;
            offC_s += ((tap_s == 3) || (tap_s == 6)) ? 94 * C : C;
#pragma unroll
            for (int r = 0; r < NSEC; ++r)
                sel[r] = ((vm[r] >> tap_s) & 1u) ? (bas[r] + offC_s) : zp;
        } else {
#pragma unroll
            for (int r = 0; r < NSEC; ++r)
                sel[r] += 32;
        }
    };

    STAGE(0);
    ADV();
    __syncthreads();

    const int swz8 = (quad ^ ((l15 >> 1) & 3)) * 8;

    auto COMPUTE = [&](auto pbc) {
        constexpr int PB = decltype(pbc)::value;
        const unsigned short* Ab = &As[0][0] + PB * 2048;
        const unsigned short* Bb = &Bs[0][0] + PB * (NT * 32);
        bf16x8 a[4], b[NSEC];
#pragma unroll
        for (int m = 0; m < 4; ++m)
            a[m] = *reinterpret_cast<const bf16x8*>(Ab + (m * 16 + l15) * 32 + swz8);
#pragma unroll
        for (int n = 0; n < NSEC; ++n)
            b[n] = *reinterpret_cast<const bf16x8*>(
                Bb + (w * (NT / 4) + n * 16 + l15) * 32 + swz8);
#pragma unroll
        for (int m = 0; m < 4; ++m)
#pragma unroll
            for (int n = 0; n < NSEC; ++n)
                acc[m][n] = __builtin_amdgcn_mfma_f32_16x16x32_bf16(
                    a[m], b[n], acc[m][n], 0, 0, 0);
    };

    for (int s = 0; s < nsteps; s += 2) {
        if (s + 1 < nsteps) { STAGE(1); ADV(); }
        COMPUTE(std::integral_constant<int, 0>{});
        __syncthreads();
        if (s + 2 < nsteps) { STAGE(0); ADV(); }
        COMPUTE(std::integral_constant<int, 1>{});
        __syncthreads();
    }

#pragma unroll
    for (int m = 0; m < 4; ++m) {
        const int co = row0 + m * 16 + quad * 4;
#pragma unroll
        for (int n = 0; n < NSEC; ++n) {
            const int pix = p0 + w * (NT / 4) + n * 16 + l15;
#pragma unroll
            for (int r = 0; r < 4; ++r) {
                const int c = co + r;
                float v = acc[m][n][r] * sc[c] + sh[c];
                out[(size_t)c * 9216 + pix] = fmaxf(v, 0.f);
            }
        }
    }
}

// ------- plain GEMM: out[B][192][9216] = attn[B][192][192] @ vT^T ----------
// Tile 64M x 256N, BK=32, 6 steps, dbuf, granule swizzle, XCD remap.
__global__ __launch_bounds__(256)
void gemm_av(const unsigned short* __restrict__ A,   // attn bf16 [B][192][192]
             const unsigned short* __restrict__ BT,  // vT bf16 [B][9216][192]
             float* __restrict__ out)
{
    constexpr int Kd = 192, NT = 256, nsteps = 6, NSEC = 4;
    __shared__ __align__(16) unsigned short As[2][64 * 32];
    __shared__ __align__(16) unsigned short Bs[2][NT * 32];

    const int tid  = threadIdx.x;
    const int w    = tid >> 6;
    const int lane = tid & 63;
    const int l15  = lane & 15, quad = lane >> 4;

    const int GX = gridDim.x, GY = gridDim.y;
    const int nwg = GX * GY * gridDim.z;
    const int orig = blockIdx.x + GX * (blockIdx.y + GY * blockIdx.z);
    const int wk = (orig & 7) * (nwg >> 3) + (orig >> 3);
    const int by = wk % GY;
    const int t2 = wk / GY;
    const int bx = t2 % GX;
    const int bz = t2 / GX;

    A   += (size_t)bz * 36864;
    BT  += (size_t)bz * 9216 * 192;
    out += (size_t)bz * 192 * 9216;

    const int row0 = by * 64;
    const int p0   = bx * NT;

    f32x4 acc[4][NSEC];
#pragma unroll
    for (int m = 0; m < 4; ++m)
#pragma unroll
        for (int n = 0; n < NSEC; ++n) acc[m][n] = {0.f, 0.f, 0.f, 0.f};

    const int srow = tid >> 2;
    const int scol = (((tid & 3) ^ ((srow >> 1) & 3)) << 3);

    const unsigned short* sA = A + (size_t)(row0 + srow) * Kd + scol;
    const unsigned short* sB[NSEC];
#pragma unroll
    for (int r = 0; r < NSEC; ++r)
        sB[r] = BT + (size_t)(p0 + 64 * r + srow) * Kd + scol;

    auto STAGE = [&](int pb) {
        gload16(sA, &As[0][0] + pb * 2048 + w * 512);
#pragma unroll
        for (int r = 0; r < NSEC; ++r)
            gload16(sB[r], &Bs[0][0] + pb * (NT * 32) + w * 512 + r * 2048);
    };
    auto ADV = [&]() {
        sA += 32;
#pragma unroll
        for (int r = 0; r < NSEC; ++r) sB[r] += 32;
    };

    STAGE(0);
    ADV();
    __syncthreads();

    const int swz8 = (quad ^ ((l15 >> 1) & 3)) * 8;

    auto COMPUTE = [&](auto pbc) {
        constexpr int PB = decltype(pbc)::value;
        const unsigned short* Ab = &As[0][0] + PB * 2048;
        const unsigned short* Bb = &Bs[0][0] + PB * (NT * 32);
        bf16x8 a[4], b[NSEC];
#pragma unroll
        for (int m = 0; m < 4; ++m)
            a[m] = *reinterpret_cast<const bf16x8*>(Ab + (m * 16 + l15) * 32 + swz8);
#pragma unroll
        for (int n = 0; n < NSEC; ++n)
            b[n] = *reinterpret_cast<const bf16x8*>(
                Bb + (w * (NT / 4) + n * 16 + l15) * 32 + swz8);
#pragma unroll
        for (int m = 0; m < 4; ++m)
#pragma unroll
            for (int n = 0; n < NSEC; ++n)
                acc[m][n] = __builtin_amdgcn_mfma_f32_16x16x32_bf16(
                    a[m], b[n], acc[m][n], 0, 0, 0);
    };

    for (int s = 0; s < nsteps; s += 2) {
        if (s + 1 < nsteps) { STAGE(1); ADV(); }
        COMPUTE(std::integral_constant<int, 0>{});
        __syncthreads();
        if (s + 2 < nsteps) { STAGE(0); ADV(); }
        COMPUTE(std::integral_constant<int, 1>{});
        __syncthreads();
    }

#pragma unroll
    for (int m = 0; m < 4; ++m) {
        const int co = row0 + m * 16 + quad * 4;
#pragma unroll
        for (int n = 0; n < NSEC; ++n) {
            const int pix = p0 + w * (NT / 4) + n * 16 + l15;
#pragma unroll
            for (int r = 0; r < 4; ++r)
                out[(size_t)(co + r) * 9216 + pix] = acc[m][n][r];
        }
    }
}

// ------- rownorms: inv L2 norm of t2 rows 0..383 (q,k); grid (384,B) -------
__global__ __launch_bounds__(256)
void rownorms(const float* __restrict__ t2, float* __restrict__ rn)
{
    const int c = blockIdx.x;
    const float* p = t2 + (size_t)blockIdx.y * 5308416 + (size_t)c * 9216;
    float s = 0.f;
    for (int i = threadIdx.x; i < 9216; i += 256) { float v = p[i]; s += v * v; }
    for (int off = 32; off; off >>= 1) s += __shfl_xor(s, off, 64);
    __shared__ float red[4];
    if ((threadIdx.x & 63) == 0) red[threadIdx.x >> 6] = s;
    __syncthreads();
    if (threadIdx.x == 0) {
        float tot = red[0] + red[1] + red[2] + red[3];
        rn[(size_t)blockIdx.y * 384 + c] = 1.f / fmaxf(sqrtf(tot), 1e-12f);
    }
}

// -------- qk split-K partial: pk[b][z][c][d], 64x64 tile, 4x4/thread -------
__global__ __launch_bounds__(256)
void qk_partial(const float* __restrict__ t2, float* __restrict__ pk)
{
    __shared__ __align__(16) float qs[32][68];
    __shared__ __align__(16) float ks[32][68];
    const int c0 = blockIdx.y * 64, d0 = blockIdx.x * 64;
    const int bz = blockIdx.z, bb = bz >> 3, chunk = bz & 7;
    const int kbase = chunk * 1152;
    const int tid = threadIdx.x, tx = tid & 15, ty = tid >> 4;
    const float* qb = t2 + (size_t)bb * 5308416;
    const float* kb = qb + (size_t)192 * 9216;

    float acc[4][4];
#pragma unroll
    for (int i = 0; i < 4; ++i)
#pragma unroll
        for (int j = 0; j < 4; ++j) acc[i][j] = 0.f;

    for (int n0 = 0; n0 < 1152; n0 += 32) {
        for (int i = tid; i < 512; i += 256) {
            int row = i >> 3, col = (i & 7) * 4;
            f32x4 v = *reinterpret_cast<const f32x4*>(
                qb + (size_t)(c0 + row) * 9216 + kbase + n0 + col);
            qs[col + 0][row] = v[0];
            qs[col + 1][row] = v[1];
            qs[col + 2][row] = v[2];
            qs[col + 3][row] = v[3];
            f32x4 w = *reinterpret_cast<const f32x4*>(
                kb + (size_t)(d0 + row) * 9216 + kbase + n0 + col);
            ks[col + 0][row] = w[0];
            ks[col + 1][row] = w[1];
            ks[col + 2][row] = w[2];
            ks[col + 3][row] = w[3];
        }
        __syncthreads();
#pragma unroll
        for (int kk = 0; kk < 32; ++kk) {
            f32x4 q4 = *reinterpret_cast<const f32x4*>(&qs[kk][ty * 4]);
            f32x4 k4 = *reinterpret_cast<const f32x4*>(&ks[kk][tx * 4]);
#pragma unroll
            for (int i = 0; i < 4; ++i)
#pragma unroll
                for (int j = 0; j < 4; ++j)
                    acc[i][j] += q4[i] * k4[j];
        }
        __syncthreads();
    }

    float* dst = pk + (size_t)bz * 36864;
#pragma unroll
    for (int i = 0; i < 4; ++i)
#pragma unroll
        for (int j = 0; j < 4; ++j)
            dst[(size_t)(c0 + ty * 4 + i) * 192 + d0 + tx * 4 + j] = acc[i][j];
}

// -------- fused reduce + scale + softmax -> BF16 attn; grid (192,B) --------
__global__ __launch_bounds__(64)
void qk_softmax(const float* __restrict__ pk, const float* __restrict__ rn,
                const float* __restrict__ temp, unsigned short* __restrict__ attn)
{
    const int r = blockIdx.x, b = blockIdx.y;
    const int t = threadIdx.x;
    const float* base = pk + (size_t)b * 8 * 36864 + (size_t)r * 192;
    float e0 = 0.f, e1 = 0.f, e2 = 0.f;
#pragma unroll
    for (int z = 0; z < 8; ++z) {
        const float* q = base + (size_t)z * 36864;
        e0 += q[t]; e1 += q[t + 64]; e2 += q[t + 128];
    }
    const float* rb = rn + (size_t)b * 384;
    const float sc = rb[r] * temp[0];
    e0 *= sc * rb[192 + t];
    e1 *= sc * rb[192 + t + 64];
    e2 *= sc * rb[192 + t + 128];
    float m = fmaxf(e0, fmaxf(e1, e2));
    for (int off = 32; off; off >>= 1) m = fmaxf(m, __shfl_xor(m, off, 64));
    e0 = __expf(e0 - m); e1 = __expf(e1 - m); e2 = __expf(e2 - m);
    float s = e0 + e1 + e2;
    for (int off = 32; off; off >>= 1) s += __shfl_xor(s, off, 64);
    float inv = 1.f / s;
    unsigned short* p = attn + (size_t)b * 36864 + (size_t)r * 192;
    bf16 h0 = __float2bfloat16(e0 * inv);
    bf16 h1 = __float2bfloat16(e1 * inv);
    bf16 h2 = __float2bfloat16(e2 * inv);
    p[t]       = *reinterpret_cast<unsigned short*>(&h0);
    p[t + 64]  = *reinterpret_cast<unsigned short*>(&h1);
    p[t + 128] = *reinterpret_cast<unsigned short*>(&h2);
}

// ---------------- depthwise 3x3 + bias -> fp32 out; grid (36,192,B) --------
__global__ __launch_bounds__(256)
void dwconv(const float* __restrict__ ao, const float* __restrict__ w2,
            const float* __restrict__ bias2, float* __restrict__ out)
{
    const int c = blockIdx.y;
    const int pix = blockIdx.x * 256 + threadIdx.x;
    const int h = pix / 96, w = pix % 96;
    const float* sp = ao + (size_t)blockIdx.z * 1769472 + (size_t)c * 9216;
    float acc = bias2[c];
#pragma unroll
    for (int kh = 0; kh < 3; ++kh) {
        int hh = h + kh - 1;
        if (hh < 0 || hh >= 96) continue;
#pragma unroll
        for (int kw = 0; kw < 3; ++kw) {
            int ww = w + kw - 1;
            if (ww < 0 || ww >= 96) continue;
            acc += w2[c * 9 + kh * 3 + kw] * sp[hh * 96 + ww];
        }
    }
    out[(size_t)blockIdx.z * 1769472 + (size_t)c * 9216 + pix] = acc;
}

extern "C" void kernel_launch(void* const* d_in, const int* in_sizes, int n_in,
                              void* d_out, int out_size, void* d_ws, size_t ws_size,
                              hipStream_t stream)
{
    float* out = (float*)d_out;

    static const int expected_sizes[16] = {
        2359296, 110592, 192, 192, 192, 192, 192,
        995328, 576, 576, 576, 576, 576, 1, 1728, 192
    };
    if (n_in != 16) {
        beacon_kernel<<<1, 256, 0, stream>>>(out, 100000.f + (float)n_in);
        return;
    }
    for (int i = 0; i < 16; ++i) {
        if (in_sizes[i] != expected_sizes[i]) {
            beacon_kernel<<<1, 256, 0, stream>>>(out, 1000.f * (float)(i + 1));
            return;
        }
    }
    if (out_size != 7077888) {
        beacon_kernel<<<1, 256, 0, stream>>>(out, 50000.f);
        return;
    }
    const size_t needed = (size_t)34913536 * 4;  // 139.65 MB
    if (ws_size < needed) {
        beacon_kernel<<<1, 256, 0, stream>>>(out, 200.f + (float)(ws_size >> 20));
        return;
    }

    const float* x    = (const float*)d_in[0];
    const float* w0   = (const float*)d_in[1];
    const float* b0   = (const float*)d_in[2];
    const float* g0   = (const float*)d_in[3];
    const float* be0  = (const float*)d_in[4];
    const float* m0   = (const float*)d_in[5];
    const float* v0   = (const float*)d_in[6];
    const float* w1   = (const float*)d_in[7];
    const float* b1   = (const float*)d_in[8];
    const float* g1   = (const float*)d_in[9];
    const float* be1  = (const float*)d_in[10];
    const float* m1   = (const float*)d_in[11];
    const float* v1   = (const float*)d_in[12];
    const float* temp = (const float*)d_in[13];
    const float* w2   = (const float*)d_in[14];
    const float* bi2  = (const float*)d_in[15];

    float* ws    = (float*)d_ws;
    float* yb    = ws;                        // 4 x 1,769,472 f
    float* t2b   = ws + 7077888;              // 4 x 5,308,416 f
    unsigned short* attnb = (unsigned short*)(ws + 28311552);  // 4 x 36,864 bf16
    float* sc0   = ws + 28459008;
    float* sh0   = ws + 28459200;
    float* sc1   = ws + 28459392;
    float* sh1   = ws + 28459968;
    float* zpf   = ws + 28460544;             // 256 f zero page
    unsigned short* zp  = (unsigned short*)zpf;
    unsigned short* A0  = (unsigned short*)(ws + 28460800);  // 110,592 bf16
    unsigned short* A1  = (unsigned short*)(ws + 28516096);  // 995,328 bf16
    unsigned short* xT  = (unsigned short*)(ws + 29013760);  // 4 x 9216x64 bf16
    unsigned short* tbT = (unsigned short*)(ws + 30193408);  // 4 x 9216x192 bf16
    unsigned short* vT  = tbT;  // alias: tbT dead after conv2
    float* pk  = ws + 33732352;               // 4 x 8 x 36864 f
    float* rn  = ws + 34912000;               // 4 x 384 f inv-norms
    float* aob = yb;  // alias: yb dead after build_tT

    wreorder_kernel<<<dim3(432), dim3(256), 0, stream>>>(w0, A0, 64, 110592);
    wreorder_kernel<<<dim3(3888), dim3(256), 0, stream>>>(w1, A1, 192, 995328);
    bnfold_kernel<<<dim3(4), dim3(256), 0, stream>>>(g0, b0, be0, m0, v0,
                                                     g1, b1, be1, m1, v1,
                                                     sc0, sh0, sc1, sh1, zpf);

    txpose_kernel<<<dim3(144, 1, 4), dim3(256), 0, stream>>>(
        x, xT, 64, (long)64 * 9216, (long)9216 * 64);
    gemm_conv<64, 128><<<dim3(72, 3, 4), dim3(256), 0, stream>>>(A0, xT, zp, sc0, sh0, yb, 192);
    build_tT<<<dim3(144, 3, 4), dim3(256), 0, stream>>>(yb, tbT);
    gemm_conv<192, 256><<<dim3(36, 9, 4), dim3(256), 0, stream>>>(A1, tbT, zp, sc1, sh1, t2b, 576);
    rownorms<<<dim3(384, 4), dim3(256), 0, stream>>>(t2b, rn);
    qk_partial<<<dim3(3, 3, 32), dim3(256), 0, stream>>>(t2b, pk);
    qk_softmax<<<dim3(192, 4), dim3(64), 0, stream>>>(pk, rn, temp, attnb);
    // vT overwrites tbT (dead after conv2); reads v-section of t2b
    txpose_kernel<<<dim3(144, 3, 4), dim3(256), 0, stream>>>(
        t2b + (size_t)384 * 9216, vT, 192, (long)5308416, (long)9216 * 192);
    gemm_av<<<dim3(36, 3, 4), dim3(256), 0, stream>>>(attnb, vT, aob);
    dwconv<<<dim3(36, 192, 4), dim3(256), 0, stream>>>(aob, w2, bi2, out);
}

// Round 14
// 418.620 us; speedup vs baseline: 1.1603x; 1.0278x over previous
//
#include <hip/hip_runtime.h>
#include <hip/hip_bf16.h>

// Round 27: mid-kernel batch.
//  * dwconv: 4 px/thread, interior fast path, float4 store (was 1 px/thread,
//    9 guarded scalar loads).
//  * rownorms kernel DELETED: conv2 epilogue accumulates row sum-of-squares
//    (shfl-reduce over l15, atomicAdd per quad-row, wave-uniform row<384
//    guard); rn zeroed in prep; qk_softmax finalizes 1/max(sqrt,eps).
//  * prep_kernel = wreorder(A0)+wreorder(A1)+bnfold+zp+rn-zero merged.
//  * gemm_av NT 256->128 (K=192 = 6 steps, latency-bound; 864 blocks now).
// conv path = round 25/26 (proven). Launches 12 -> 10.
// ws layout (floats), total 34,913,536 f = 139.65 MB:
//   yb[0,7077888) t2b[..,28311552) attnb(ushort)[..,28459008)
//   sc0@28459008 sh0@28459200 sc1@28459392 sh1@28459968 zp@28460544 (256 f)
//   A0 ush @f 28460800 | A1 ush @f 28516096
//   xT ush @f 29013760 | tbT/vT ush @f 30193408
//   pk [33732352, 34912000) | rn [34912000, 34913536)  (raw sum-of-squares)

typedef __hip_bfloat16 bf16;
typedef short bf16x8 __attribute__((ext_vector_type(8)));
typedef float f32x4 __attribute__((ext_vector_type(4)));

typedef const __attribute__((address_space(1))) unsigned short* gas_ptr;
typedef __attribute__((address_space(3))) unsigned short* las_ptr;

__device__ __forceinline__ void gload16(const unsigned short* g, unsigned short* l)
{
    __builtin_amdgcn_global_load_lds((gas_ptr)g, (las_ptr)l, 16, 0, 0);
}

__device__ __forceinline__ unsigned short f2bf(float v)
{
    bf16 h = __float2bfloat16(v);
    return *reinterpret_cast<unsigned short*>(&h);
}

__global__ void beacon_kernel(float* out, float val)
{
    out[threadIdx.x] = val;
}

// ------- prep: weight reorders + BN fold + zero page + rn zero -------------
// ranges: [0,110592) A0 | [..,1105920) A1 | 192 sc0/sh0 | 576 sc1/sh1 |
//         256 zp | 1536 rn. grid 4330 x 256.
__global__ __launch_bounds__(256)
void prep_kernel(const float* __restrict__ w0s, const float* __restrict__ w1s,
                 const float* g0, const float* b0, const float* be0,
                 const float* m0, const float* v0,
                 const float* g1, const float* b1, const float* be1,
                 const float* m1, const float* v1,
                 unsigned short* __restrict__ A0, unsigned short* __restrict__ A1,
                 float* sc0, float* sh0, float* sc1, float* sh1,
                 float* zpf, float* rn)
{
    int i = blockIdx.x * 256 + threadIdx.x;
    if (i < 110592) {
        int o = i / 576, r = i % 576, tap = r / 64, ci = r % 64;
        A0[i] = f2bf(w0s[(size_t)o * 576 + ci * 9 + tap]);
    } else if (i < 1105920) {
        int j = i - 110592;
        int o = j / 1728, r = j % 1728, tap = r / 192, ci = r % 192;
        A1[j] = f2bf(w1s[(size_t)o * 1728 + ci * 9 + tap]);
    } else if (i < 1106112) {
        int c = i - 1105920;
        float s = g0[c] * rsqrtf(v0[c] + 1e-5f);
        sc0[c] = s;
        sh0[c] = (b0[c] - m0[c]) * s + be0[c];
    } else if (i < 1106688) {
        int c = i - 1106112;
        float s = g1[c] * rsqrtf(v1[c] + 1e-5f);
        sc1[c] = s;
        sh1[c] = (b1[c] - m1[c]) * s + be1[c];
    } else if (i < 1106944) {
        zpf[i - 1106688] = 0.f;
    } else if (i < 1108480) {
        rn[i - 1106944] = 0.f;
    }
}

// ------- transpose: src f32 [C][9216] -> dst bf16 [9216][C]; grid (144,C/64,B)
__global__ __launch_bounds__(256)
void txpose_kernel(const float* __restrict__ src, unsigned short* __restrict__ dst,
                   int C, long sbs, long dbs)
{
    __shared__ float tile[64][65];
    const int p0 = blockIdx.x * 64, c0 = blockIdx.y * 64;
    src += (size_t)blockIdx.z * sbs;
    dst += (size_t)blockIdx.z * dbs;
    for (int i = threadIdx.x; i < 4096; i += 256) {
        int r = i >> 6, c = i & 63;
        tile[c][r] = src[(size_t)(c0 + r) * 9216 + p0 + c];
    }
    __syncthreads();
    for (int i = threadIdx.x; i < 2048; i += 256) {
        int p = i >> 5, cp = (i & 31) * 2;
        unsigned int u = (unsigned int)f2bf(tile[p][cp])
                       | ((unsigned int)f2bf(tile[p][cp + 1]) << 16);
        *reinterpret_cast<unsigned int*>(dst + (size_t)(p0 + p) * C + c0 + cp) = u;
    }
}

// ------- fused build_t + transpose -> tbT bf16 [B][9216][192]; grid (144,3,B)
__global__ __launch_bounds__(256)
void build_tT(const float* __restrict__ y, unsigned short* __restrict__ tbT)
{
    __shared__ float tile[64][65];
    const int p0 = blockIdx.x * 64, c0 = blockIdx.y * 64;
    y += (size_t)blockIdx.z * 192 * 9216;
    tbT += (size_t)blockIdx.z * 9216 * 192;
    for (int i = threadIdx.x; i < 4096; i += 256) {
        int r = i >> 6, pcol = i & 63;
        const int c = c0 + r;
        const int pix = p0 + pcol;
        const float* yp = y + (size_t)c * 9216;
        float val;
        if (c0 == 64) {
            val = yp[pix];
        } else {
            const int oh = pix / 96, ow = pix % 96;
            float fh = fminf(fmaxf(oh * 0.5f - 0.25f, 0.f), 47.f);
            float fw = fminf(fmaxf(ow * 0.5f - 0.25f, 0.f), 47.f);
            int hlo = (int)floorf(fh);
            int wlo = (int)floorf(fw);
            int hhi = (hlo < 47) ? hlo + 1 : 47;
            int whi = (wlo < 47) ? wlo + 1 : 47;
            float ff = fh - (float)hlo;
            float fg = fw - (float)wlo;
            int hs[2] = {hlo, hhi}, wss[2] = {wlo, whi};
            float p[2][2];
            for (int a = 0; a < 2; ++a)
                for (int e = 0; e < 2; ++e) {
                    const float* q = yp + (hs[a] * 2) * 96 + wss[e] * 2;
                    float v00 = q[0], v01 = q[1], v10 = q[96], v11 = q[97];
                    p[a][e] = (c0 == 0)
                        ? fmaxf(fmaxf(v00, v01), fmaxf(v10, v11))
                        : 0.25f * (v00 + v01 + v10 + v11);
                }
            val = (p[0][0] * (1.f - ff) + p[1][0] * ff) * (1.f - fg)
                + (p[0][1] * (1.f - ff) + p[1][1] * ff) * fg;
        }
        tile[pcol][r] = val;
    }
    __syncthreads();
    for (int i = threadIdx.x; i < 2048; i += 256) {
        int p = i >> 5, cp = (i & 31) * 2;
        unsigned int u = (unsigned int)f2bf(tile[p][cp])
                       | ((unsigned int)f2bf(tile[p][cp + 1]) << 16);
        *reinterpret_cast<unsigned int*>(tbT + (size_t)(p0 + p) * 192 + c0 + cp) = u;
    }
}

// ------- implicit-im2col GEMM v8 = v7 + optional row-sumsq in epilogue -----
template<int C, int NT, bool DO_NORM>
__global__ __launch_bounds__(256)
void gemm_conv(const unsigned short* __restrict__ A,
               const unsigned short* __restrict__ BT,
               const unsigned short* __restrict__ zp,
               const float* __restrict__ sc, const float* __restrict__ sh,
               float* __restrict__ out, int M, float* __restrict__ rn)
{
    constexpr int K = 9 * C;
    constexpr int nsteps = K / 32;
    constexpr int NSEC = NT / 64;

    __shared__ __align__(16) unsigned short As[2][64 * 32];
    __shared__ __align__(16) unsigned short Bs[2][NT * 32];

    const int tid  = threadIdx.x;
    const int w    = tid >> 6;
    const int lane = tid & 63;
    const int l15  = lane & 15, quad = lane >> 4;

    const int GX = gridDim.x, GY = gridDim.y;
    const int nwg = GX * GY * gridDim.z;
    const int orig = blockIdx.x + GX * (blockIdx.y + GY * blockIdx.z);
    const int wk = (orig & 7) * (nwg >> 3) + (orig >> 3);
    const int by = wk % GY;
    const int t2 = wk / GY;
    const int bx = t2 % GX;
    const int bz = t2 / GX;

    BT  += (size_t)bz * 9216 * C;
    out += (size_t)bz * (size_t)M * 9216;

    const int row0 = by * 64;
    const int p0   = bx * NT;

    f32x4 acc[4][NSEC];
#pragma unroll
    for (int m = 0; m < 4; ++m)
#pragma unroll
        for (int n = 0; n < NSEC; ++n) acc[m][n] = {0.f, 0.f, 0.f, 0.f};

    const int srow = tid >> 2;
    const int scol = (((tid & 3) ^ ((srow >> 1) & 3)) << 3);

    const unsigned short* sA = A + (size_t)(row0 + srow) * K + scol;

    const unsigned short* bas[NSEC];
    unsigned vm[NSEC];
    {
        int hB[NSEC], wB[NSEC];
#pragma unroll
        for (int r = 0; r < NSEC; ++r) {
            int pB = p0 + 64 * r + srow;
            hB[r] = pB / 96; wB[r] = pB % 96;
            bas[r] = BT + (size_t)pB * C + scol;
            vm[r] = 0u;
        }
#pragma unroll
        for (int tap = 0; tap < 9; ++tap) {
            const int dh = tap / 3 - 1, dw = tap % 3 - 1;
#pragma unroll
            for (int r = 0; r < NSEC; ++r)
                vm[r] |= (unsigned)(((unsigned)(hB[r] + dh) < 96u) &&
                                    ((unsigned)(wB[r] + dw) < 96u)) << tap;
        }
    }

    int tap_s = 0, kk_s = 0;
    int offC_s = -97 * C;
    const unsigned short* sel[NSEC];
#pragma unroll
    for (int r = 0; r < NSEC; ++r)
        sel[r] = (vm[r] & 1u) ? (bas[r] + offC_s) : zp;

    auto STAGE = [&](int pb) {
        gload16(sA, &As[0][0] + pb * 2048 + w * 512);
#pragma unroll
        for (int r = 0; r < NSEC; ++r)
            gload16(sel[r], &Bs[0][0] + pb * (NT * 32) + w * 512 + r * 2048);
    };
    auto ADV = [&]() {
        sA += 32;
        kk_s += 32;
        if (kk_s == C) {
            kk_s = 0; ++tap_s;
            offC_s += ((tap_s == 3) || (tap_s == 6)) ? 94 * C : C;
#pragma unroll
            for (int r = 0; r < NSEC; ++r)
                sel[r] = ((vm[r] >> tap_s) & 1u) ? (bas[r] + offC_s) : zp;
        } else {
#pragma unroll
            for (int r = 0; r < NSEC; ++r)
                sel[r] += 32;
        }
    };

    STAGE(0);
    ADV();
    __syncthreads();

    const int swz8 = (quad ^ ((l15 >> 1) & 3)) * 8;

    auto COMPUTE = [&](auto pbc) {
        constexpr int PB = decltype(pbc)::value;
        const unsigned short* Ab = &As[0][0] + PB * 2048;
        const unsigned short* Bb = &Bs[0][0] + PB * (NT * 32);
        bf16x8 a[4], b[NSEC];
#pragma unroll
        for (int m = 0; m < 4; ++m)
            a[m] = *reinterpret_cast<const bf16x8*>(Ab + (m * 16 + l15) * 32 + swz8);
#pragma unroll
        for (int n = 0; n < NSEC; ++n)
            b[n] = *reinterpret_cast<const bf16x8*>(
                Bb + (w * (NT / 4) + n * 16 + l15) * 32 + swz8);
#pragma unroll
        for (int m = 0; m < 4; ++m)
#pragma unroll
            for (int n = 0; n < NSEC; ++n)
                acc[m][n] = __builtin_amdgcn_mfma_f32_16x16x32_bf16(
                    a[m], b[n], acc[m][n], 0, 0, 0);
    };

    for (int s = 0; s < nsteps; s += 2) {
        if (s + 1 < nsteps) { STAGE(1); ADV(); }
        COMPUTE(std::integral_constant<int, 0>{});
        __syncthreads();
        if (s + 2 < nsteps) { STAGE(0); ADV(); }
        COMPUTE(std::integral_constant<int, 1>{});
        __syncthreads();
    }

#pragma unroll
    for (int m = 0; m < 4; ++m) {
        const int co = row0 + m * 16 + quad * 4;
#pragma unroll
        for (int r = 0; r < 4; ++r) {
            const int c = co + r;
            const float scl = sc[c], shf = sh[c];
            float sq = 0.f;
#pragma unroll
            for (int n = 0; n < NSEC; ++n) {
                const int pix = p0 + w * (NT / 4) + n * 16 + l15;
                float v = fmaxf(acc[m][n][r] * scl + shf, 0.f);
                out[(size_t)c * 9216 + pix] = v;
                sq += v * v;
            }
            if constexpr (DO_NORM) {
                if (row0 + m * 16 < 384) {     // wave-uniform (16-aligned tiles)
                    sq += __shfl_xor(sq, 1);
                    sq += __shfl_xor(sq, 2);
                    sq += __shfl_xor(sq, 4);
                    sq += __shfl_xor(sq, 8);
                    if (l15 == 0)
                        atomicAdd(rn + (size_t)bz * 384 + c, sq);
                }
            }
        }
    }
}

// ------- plain GEMM: out[B][192][9216] = attn @ vT^T; NT=128, 6 steps ------
__global__ __launch_bounds__(256)
void gemm_av(const unsigned short* __restrict__ A,   // attn bf16 [B][192][192]
             const unsigned short* __restrict__ BT,  // vT bf16 [B][9216][192]
             float* __restrict__ out)
{
    constexpr int Kd = 192, NT = 128, nsteps = 6, NSEC = 2;
    __shared__ __align__(16) unsigned short As[2][64 * 32];
    __shared__ __align__(16) unsigned short Bs[2][NT * 32];

    const int tid  = threadIdx.x;
    const int w    = tid >> 6;
    const int lane = tid & 63;
    const int l15  = lane & 15, quad = lane >> 4;

    const int GX = gridDim.x, GY = gridDim.y;
    const int nwg = GX * GY * gridDim.z;
    const int orig = blockIdx.x + GX * (blockIdx.y + GY * blockIdx.z);
    const int wk = (orig & 7) * (nwg >> 3) + (orig >> 3);
    const int by = wk % GY;
    const int t2 = wk / GY;
    const int bx = t2 % GX;
    const int bz = t2 / GX;

    A   += (size_t)bz * 36864;
    BT  += (size_t)bz * 9216 * 192;
    out += (size_t)bz * 192 * 9216;

    const int row0 = by * 64;
    const int p0   = bx * NT;

    f32x4 acc[4][NSEC];
#pragma unroll
    for (int m = 0; m < 4; ++m)
#pragma unroll
        for (int n = 0; n < NSEC; ++n) acc[m][n] = {0.f, 0.f, 0.f, 0.f};

    const int srow = tid >> 2;
    const int scol = (((tid & 3) ^ ((srow >> 1) & 3)) << 3);

    const unsigned short* sA = A + (size_t)(row0 + srow) * Kd + scol;
    const unsigned short* sB[NSEC];
#pragma unroll
    for (int r = 0; r < NSEC; ++r)
        sB[r] = BT + (size_t)(p0 + 64 * r + srow) * Kd + scol;

    auto STAGE = [&](int pb) {
        gload16(sA, &As[0][0] + pb * 2048 + w * 512);
#pragma unroll
        for (int r = 0; r < NSEC; ++r)
            gload16(sB[r], &Bs[0][0] + pb * (NT * 32) + w * 512 + r * 2048);
    };
    auto ADV = [&]() {
        sA += 32;
#pragma unroll
        for (int r = 0; r < NSEC; ++r) sB[r] += 32;
    };

    STAGE(0);
    ADV();
    __syncthreads();

    const int swz8 = (quad ^ ((l15 >> 1) & 3)) * 8;

    auto COMPUTE = [&](auto pbc) {
        constexpr int PB = decltype(pbc)::value;
        const unsigned short* Ab = &As[0][0] + PB * 2048;
        const unsigned short* Bb = &Bs[0][0] + PB * (NT * 32);
        bf16x8 a[4], b[NSEC];
#pragma unroll
        for (int m = 0; m < 4; ++m)
            a[m] = *reinterpret_cast<const bf16x8*>(Ab + (m * 16 + l15) * 32 + swz8);
#pragma unroll
        for (int n = 0; n < NSEC; ++n)
            b[n] = *reinterpret_cast<const bf16x8*>(
                Bb + (w * (NT / 4) + n * 16 + l15) * 32 + swz8);
#pragma unroll
        for (int m = 0; m < 4; ++m)
#pragma unroll
            for (int n = 0; n < NSEC; ++n)
                acc[m][n] = __builtin_amdgcn_mfma_f32_16x16x32_bf16(
                    a[m], b[n], acc[m][n], 0, 0, 0);
    };

    for (int s = 0; s < nsteps; s += 2) {
        if (s + 1 < nsteps) { STAGE(1); ADV(); }
        COMPUTE(std::integral_constant<int, 0>{});
        __syncthreads();
        if (s + 2 < nsteps) { STAGE(0); ADV(); }
        COMPUTE(std::integral_constant<int, 1>{});
        __syncthreads();
    }

#pragma unroll
    for (int m = 0; m < 4; ++m) {
        const int co = row0 + m * 16 + quad * 4;
#pragma unroll
        for (int n = 0; n < NSEC; ++n) {
            const int pix = p0 + w * (NT / 4) + n * 16 + l15;
#pragma unroll
            for (int r = 0; r < 4; ++r)
                out[(size_t)(co + r) * 9216 + pix] = acc[m][n][r];
        }
    }
}

// -------- qk split-K partial: pk[b][z][c][d], 64x64 tile, 4x4/thread -------
__global__ __launch_bounds__(256)
void qk_partial(const float* __restrict__ t2, float* __restrict__ pk)
{
    __shared__ __align__(16) float qs[32][68];
    __shared__ __align__(16) float ks[32][68];
    const int c0 = blockIdx.y * 64, d0 = blockIdx.x * 64;
    const int bz = blockIdx.z, bb = bz >> 3, chunk = bz & 7;
    const int kbase = chunk * 1152;
    const int tid = threadIdx.x, tx = tid & 15, ty = tid >> 4;
    const float* qb = t2 + (size_t)bb * 5308416;
    const float* kb = qb + (size_t)192 * 9216;

    float acc[4][4];
#pragma unroll
    for (int i = 0; i < 4; ++i)
#pragma unroll
        for (int j = 0; j < 4; ++j) acc[i][j] = 0.f;

    for (int n0 = 0; n0 < 1152; n0 += 32) {
        for (int i = tid; i < 512; i += 256) {
            int row = i >> 3, col = (i & 7) * 4;
            f32x4 v = *reinterpret_cast<const f32x4*>(
                qb + (size_t)(c0 + row) * 9216 + kbase + n0 + col);
            qs[col + 0][row] = v[0];
            qs[col + 1][row] = v[1];
            qs[col + 2][row] = v[2];
            qs[col + 3][row] = v[3];
            f32x4 w = *reinterpret_cast<const f32x4*>(
                kb + (size_t)(d0 + row) * 9216 + kbase + n0 + col);
            ks[col + 0][row] = w[0];
            ks[col + 1][row] = w[1];
            ks[col + 2][row] = w[2];
            ks[col + 3][row] = w[3];
        }
        __syncthreads();
#pragma unroll
        for (int kk = 0; kk < 32; ++kk) {
            f32x4 q4 = *reinterpret_cast<const f32x4*>(&qs[kk][ty * 4]);
            f32x4 k4 = *reinterpret_cast<const f32x4*>(&ks[kk][tx * 4]);
#pragma unroll
            for (int i = 0; i < 4; ++i)
#pragma unroll
                for (int j = 0; j < 4; ++j)
                    acc[i][j] += q4[i] * k4[j];
        }
        __syncthreads();
    }

    float* dst = pk + (size_t)bz * 36864;
#pragma unroll
    for (int i = 0; i < 4; ++i)
#pragma unroll
        for (int j = 0; j < 4; ++j)
            dst[(size_t)(c0 + ty * 4 + i) * 192 + d0 + tx * 4 + j] = acc[i][j];
}

// -------- fused reduce + norm-finalize + scale + softmax -> BF16 attn ------
// grid (192,B); rn holds raw sum-of-squares.
__global__ __launch_bounds__(64)
void qk_softmax(const float* __restrict__ pk, const float* __restrict__ rn,
                const float* __restrict__ temp, unsigned short* __restrict__ attn)
{
    const int r = blockIdx.x, b = blockIdx.y;
    const int t = threadIdx.x;
    const float* base = pk + (size_t)b * 8 * 36864 + (size_t)r * 192;
    float e0 = 0.f, e1 = 0.f, e2 = 0.f;
#pragma unroll
    for (int z = 0; z < 8; ++z) {
        const float* q = base + (size_t)z * 36864;
        e0 += q[t]; e1 += q[t + 64]; e2 += q[t + 128];
    }
    const float* rb = rn + (size_t)b * 384;
    const float invq = 1.f / fmaxf(sqrtf(rb[r]), 1e-12f);
    const float sc = invq * temp[0];
    e0 *= sc / fmaxf(sqrtf(rb[192 + t]), 1e-12f);
    e1 *= sc / fmaxf(sqrtf(rb[192 + t + 64]), 1e-12f);
    e2 *= sc / fmaxf(sqrtf(rb[192 + t + 128]), 1e-12f);
    float m = fmaxf(e0, fmaxf(e1, e2));
    for (int off = 32; off; off >>= 1) m = fmaxf(m, __shfl_xor(m, off, 64));
    e0 = __expf(e0 - m); e1 = __expf(e1 - m); e2 = __expf(e2 - m);
    float s = e0 + e1 + e2;
    for (int off = 32; off; off >>= 1) s += __shfl_xor(s, off, 64);
    float inv = 1.f / s;
    unsigned short* p = attn + (size_t)b * 36864 + (size_t)r * 192;
    p[t]       = f2bf(e0 * inv);
    p[t + 64]  = f2bf(e1 * inv);
    p[t + 128] = f2bf(e2 * inv);
}

// ---------------- depthwise 3x3 + bias; 4 px/thread; grid (9,192,B) --------
__global__ __launch_bounds__(256)
void dwconv(const float* __restrict__ ao, const float* __restrict__ w2,
            const float* __restrict__ bias2, float* __restrict__ out)
{
    const int c = blockIdx.y;
    const int p4 = blockIdx.x * 1024 + threadIdx.x * 4;   // 4-px group, w0 % 4 == 0
    const int h = p4 / 96, w0 = p4 % 96;
    const float* sp = ao + (size_t)blockIdx.z * 1769472 + (size_t)c * 9216;
    float wgt[9];
#pragma unroll
    for (int i = 0; i < 9; ++i) wgt[i] = w2[c * 9 + i];
    const float bv = bias2[c];
    float a0 = bv, a1 = bv, a2 = bv, a3 = bv;

    if (h >= 1 && h <= 94 && w0 >= 4 && w0 <= 88) {
#pragma unroll
        for (int kh = 0; kh < 3; ++kh) {
            const float* rp = sp + (h + kh - 1) * 96 + w0 - 1;
            float f0 = rp[0], f1 = rp[1], f2 = rp[2];
            float f3 = rp[3], f4 = rp[4], f5 = rp[5];
            float g0 = wgt[kh * 3], g1 = wgt[kh * 3 + 1], g2 = wgt[kh * 3 + 2];
            a0 += g0 * f0 + g1 * f1 + g2 * f2;
            a1 += g0 * f1 + g1 * f2 + g2 * f3;
            a2 += g0 * f2 + g1 * f3 + g2 * f4;
            a3 += g0 * f3 + g1 * f4 + g2 * f5;
        }
    } else {
        float aa[4] = {bv, bv, bv, bv};
#pragma unroll
        for (int j = 0; j < 4; ++j) {
            const int w = w0 + j;
#pragma unroll
            for (int kh = 0; kh < 3; ++kh) {
                int hh = h + kh - 1;
                if ((unsigned)hh >= 96u) continue;
#pragma unroll
                for (int kw = 0; kw < 3; ++kw) {
                    int ww = w + kw - 1;
                    if ((unsigned)ww >= 96u) continue;
                    aa[j] += wgt[kh * 3 + kw] * sp[hh * 96 + ww];
                }
            }
        }
        a0 = aa[0]; a1 = aa[1]; a2 = aa[2]; a3 = aa[3];
    }

    f32x4 o = {a0, a1, a2, a3};
    *reinterpret_cast<f32x4*>(
        out + (size_t)blockIdx.z * 1769472 + (size_t)c * 9216 + p4) = o;
}

extern "C" void kernel_launch(void* const* d_in, const int* in_sizes, int n_in,
                              void* d_out, int out_size, void* d_ws, size_t ws_size,
                              hipStream_t stream)
{
    float* out = (float*)d_out;

    static const int expected_sizes[16] = {
        2359296, 110592, 192, 192, 192, 192, 192,
        995328, 576, 576, 576, 576, 576, 1, 1728, 192
    };
    if (n_in != 16) {
        beacon_kernel<<<1, 256, 0, stream>>>(out, 100000.f + (float)n_in);
        return;
    }
    for (int i = 0; i < 16; ++i) {
        if (in_sizes[i] != expected_sizes[i]) {
            beacon_kernel<<<1, 256, 0, stream>>>(out, 1000.f * (float)(i + 1));
            return;
        }
    }
    if (out_size != 7077888) {
        beacon_kernel<<<1, 256, 0, stream>>>(out, 50000.f);
        return;
    }
    const size_t needed = (size_t)34913536 * 4;  // 139.65 MB
    if (ws_size < needed) {
        beacon_kernel<<<1, 256, 0, stream>>>(out, 200.f + (float)(ws_size >> 20));
        return;
    }

    const float* x    = (const float*)d_in[0];
    const float* w0   = (const float*)d_in[1];
    const float* b0   = (const float*)d_in[2];
    const float* g0   = (const float*)d_in[3];
    const float* be0  = (const float*)d_in[4];
    const float* m0   = (const float*)d_in[5];
    const float* v0   = (const float*)d_in[6];
    const float* w1   = (const float*)d_in[7];
    const float* b1   = (const float*)d_in[8];
    const float* g1   = (const float*)d_in[9];
    const float* be1  = (const float*)d_in[10];
    const float* m1   = (const float*)d_in[11];
    const float* v1   = (const float*)d_in[12];
    const float* temp = (const float*)d_in[13];
    const float* w2   = (const float*)d_in[14];
    const float* bi2  = (const float*)d_in[15];

    float* ws    = (float*)d_ws;
    float* yb    = ws;                        // 4 x 1,769,472 f
    float* t2b   = ws + 7077888;              // 4 x 5,308,416 f
    unsigned short* attnb = (unsigned short*)(ws + 28311552);  // 4 x 36,864 bf16
    float* sc0   = ws + 28459008;
    float* sh0   = ws + 28459200;
    float* sc1   = ws + 28459392;
    float* sh1   = ws + 28459968;
    float* zpf   = ws + 28460544;             // 256 f zero page
    unsigned short* zp  = (unsigned short*)zpf;
    unsigned short* A0  = (unsigned short*)(ws + 28460800);  // 110,592 bf16
    unsigned short* A1  = (unsigned short*)(ws + 28516096);  // 995,328 bf16
    unsigned short* xT  = (unsigned short*)(ws + 29013760);  // 4 x 9216x64 bf16
    unsigned short* tbT = (unsigned short*)(ws + 30193408);  // 4 x 9216x192 bf16
    unsigned short* vT  = tbT;  // alias: tbT dead after conv2
    float* pk  = ws + 33732352;               // 4 x 8 x 36864 f
    float* rn  = ws + 34912000;               // 4 x 384 f raw sum-of-squares
    float* aob = yb;  // alias: yb dead after build_tT

    prep_kernel<<<dim3(4330), dim3(256), 0, stream>>>(
        w0, w1, g0, b0, be0, m0, v0, g1, b1, be1, m1, v1,
        A0, A1, sc0, sh0, sc1, sh1, zpf, rn);

    txpose_kernel<<<dim3(144, 1, 4), dim3(256), 0, stream>>>(
        x, xT, 64, (long)64 * 9216, (long)9216 * 64);
    gemm_conv<64, 128, false><<<dim3(72, 3, 4), dim3(256), 0, stream>>>(
        A0, xT, zp, sc0, sh0, yb, 192, nullptr);
    build_tT<<<dim3(144, 3, 4), dim3(256), 0, stream>>>(yb, tbT);
    gemm_conv<192, 256, true><<<dim3(36, 9, 4), dim3(256), 0, stream>>>(
        A1, tbT, zp, sc1, sh1, t2b, 576, rn);
    qk_partial<<<dim3(3, 3, 32), dim3(256), 0, stream>>>(t2b, pk);
    qk_softmax<<<dim3(192, 4), dim3(64), 0, stream>>>(pk, rn, temp, attnb);
    // vT overwrites tbT (dead after conv2); reads v-section of t2b
    txpose_kernel<<<dim3(144, 3, 4), dim3(256), 0, stream>>>(
        t2b + (size_t)384 * 9216, vT, 192, (long)5308416, (long)9216 * 192);
    gemm_av<<<dim3(72, 3, 4), dim3(256), 0, stream>>>(attnb, vT, aob);
    dwconv<<<dim3(9, 192, 4), dim3(256), 0, stream>>>(aob, w2, bi2, out);
}

// Round 15
// 358.427 us; speedup vs baseline: 1.3552x; 1.1679x over previous
//
#include <hip/hip_runtime.h>
#include <hip/hip_bf16.h>

// Round 28: (a) DO_NORM epilogue REVERTED (r14: conv2 130->147, atomics cost
// more than the kernel they replaced). (b) QK^T -> bf16 MFMA GEMM:
//   qk_cast: q,k rows f32 -> bf16 qkb[b][384][9216] (ALIASED into dead yb
//     slot, exact fit) + direct rn sum-of-squares store (no atomics).
//   gemm_qk: 64x64 tile, split-K 8x1152 (36 steps), v5 staging/swizzle/dbuf,
//     grid (3,3,32), writes pk[b][z][c][d] (qk_softmax unchanged).
//   f32 qk_partial deleted (was ~45us VALU-bound; no f32 MFMA exists).
// dwconv/prep/gemm_av(NT=128) kept from r27. Launches 11.
// ws layout (floats), total 34,913,536 f = 139.65 MB:
//   yb/qkb/aob[0,7077888) t2b[..,28311552) attnb(ushort)[..,28459008)
//   sc0@28459008 sh0@28459200 sc1@28459392 sh1@28459968 zp@28460544 (256 f)
//   A0 ush @f 28460800 | A1 ush @f 28516096
//   xT ush @f 29013760 | tbT/vT ush @f 30193408
//   pk [33732352, 34912000) | rn [34912000, 34913536) (raw sum-of-squares)

typedef __hip_bfloat16 bf16;
typedef short bf16x8 __attribute__((ext_vector_type(8)));
typedef float f32x4 __attribute__((ext_vector_type(4)));

typedef const __attribute__((address_space(1))) unsigned short* gas_ptr;
typedef __attribute__((address_space(3))) unsigned short* las_ptr;

__device__ __forceinline__ void gload16(const unsigned short* g, unsigned short* l)
{
    __builtin_amdgcn_global_load_lds((gas_ptr)g, (las_ptr)l, 16, 0, 0);
}

__device__ __forceinline__ unsigned short f2bf(float v)
{
    bf16 h = __float2bfloat16(v);
    return *reinterpret_cast<unsigned short*>(&h);
}

__global__ void beacon_kernel(float* out, float val)
{
    out[threadIdx.x] = val;
}

// ------- prep: weight reorders + BN fold + zero page + rn zero -------------
__global__ __launch_bounds__(256)
void prep_kernel(const float* __restrict__ w0s, const float* __restrict__ w1s,
                 const float* g0, const float* b0, const float* be0,
                 const float* m0, const float* v0,
                 const float* g1, const float* b1, const float* be1,
                 const float* m1, const float* v1,
                 unsigned short* __restrict__ A0, unsigned short* __restrict__ A1,
                 float* sc0, float* sh0, float* sc1, float* sh1,
                 float* zpf, float* rn)
{
    int i = blockIdx.x * 256 + threadIdx.x;
    if (i < 110592) {
        int o = i / 576, r = i % 576, tap = r / 64, ci = r % 64;
        A0[i] = f2bf(w0s[(size_t)o * 576 + ci * 9 + tap]);
    } else if (i < 1105920) {
        int j = i - 110592;
        int o = j / 1728, r = j % 1728, tap = r / 192, ci = r % 192;
        A1[j] = f2bf(w1s[(size_t)o * 1728 + ci * 9 + tap]);
    } else if (i < 1106112) {
        int c = i - 1105920;
        float s = g0[c] * rsqrtf(v0[c] + 1e-5f);
        sc0[c] = s;
        sh0[c] = (b0[c] - m0[c]) * s + be0[c];
    } else if (i < 1106688) {
        int c = i - 1106112;
        float s = g1[c] * rsqrtf(v1[c] + 1e-5f);
        sc1[c] = s;
        sh1[c] = (b1[c] - m1[c]) * s + be1[c];
    } else if (i < 1106944) {
        zpf[i - 1106688] = 0.f;
    } else if (i < 1108480) {
        rn[i - 1106944] = 0.f;
    }
}

// ------- transpose: src f32 [C][9216] -> dst bf16 [9216][C]; grid (144,C/64,B)
__global__ __launch_bounds__(256)
void txpose_kernel(const float* __restrict__ src, unsigned short* __restrict__ dst,
                   int C, long sbs, long dbs)
{
    __shared__ float tile[64][65];
    const int p0 = blockIdx.x * 64, c0 = blockIdx.y * 64;
    src += (size_t)blockIdx.z * sbs;
    dst += (size_t)blockIdx.z * dbs;
    for (int i = threadIdx.x; i < 4096; i += 256) {
        int r = i >> 6, c = i & 63;
        tile[c][r] = src[(size_t)(c0 + r) * 9216 + p0 + c];
    }
    __syncthreads();
    for (int i = threadIdx.x; i < 2048; i += 256) {
        int p = i >> 5, cp = (i & 31) * 2;
        unsigned int u = (unsigned int)f2bf(tile[p][cp])
                       | ((unsigned int)f2bf(tile[p][cp + 1]) << 16);
        *reinterpret_cast<unsigned int*>(dst + (size_t)(p0 + p) * C + c0 + cp) = u;
    }
}

// ------- fused build_t + transpose -> tbT bf16 [B][9216][192]; grid (144,3,B)
__global__ __launch_bounds__(256)
void build_tT(const float* __restrict__ y, unsigned short* __restrict__ tbT)
{
    __shared__ float tile[64][65];
    const int p0 = blockIdx.x * 64, c0 = blockIdx.y * 64;
    y += (size_t)blockIdx.z * 192 * 9216;
    tbT += (size_t)blockIdx.z * 9216 * 192;
    for (int i = threadIdx.x; i < 4096; i += 256) {
        int r = i >> 6, pcol = i & 63;
        const int c = c0 + r;
        const int pix = p0 + pcol;
        const float* yp = y + (size_t)c * 9216;
        float val;
        if (c0 == 64) {
            val = yp[pix];
        } else {
            const int oh = pix / 96, ow = pix % 96;
            float fh = fminf(fmaxf(oh * 0.5f - 0.25f, 0.f), 47.f);
            float fw = fminf(fmaxf(ow * 0.5f - 0.25f, 0.f), 47.f);
            int hlo = (int)floorf(fh);
            int wlo = (int)floorf(fw);
            int hhi = (hlo < 47) ? hlo + 1 : 47;
            int whi = (wlo < 47) ? wlo + 1 : 47;
            float ff = fh - (float)hlo;
            float fg = fw - (float)wlo;
            int hs[2] = {hlo, hhi}, wss[2] = {wlo, whi};
            float p[2][2];
            for (int a = 0; a < 2; ++a)
                for (int e = 0; e < 2; ++e) {
                    const float* q = yp + (hs[a] * 2) * 96 + wss[e] * 2;
                    float v00 = q[0], v01 = q[1], v10 = q[96], v11 = q[97];
                    p[a][e] = (c0 == 0)
                        ? fmaxf(fmaxf(v00, v01), fmaxf(v10, v11))
                        : 0.25f * (v00 + v01 + v10 + v11);
                }
            val = (p[0][0] * (1.f - ff) + p[1][0] * ff) * (1.f - fg)
                + (p[0][1] * (1.f - ff) + p[1][1] * ff) * fg;
        }
        tile[pcol][r] = val;
    }
    __syncthreads();
    for (int i = threadIdx.x; i < 2048; i += 256) {
        int p = i >> 5, cp = (i & 31) * 2;
        unsigned int u = (unsigned int)f2bf(tile[p][cp])
                       | ((unsigned int)f2bf(tile[p][cp + 1]) << 16);
        *reinterpret_cast<unsigned int*>(tbT + (size_t)(p0 + p) * 192 + c0 + cp) = u;
    }
}

// ------- implicit-im2col GEMM v7 (round-25/26 proven body) -----------------
template<int C, int NT>
__global__ __launch_bounds__(256)
void gemm_conv(const unsigned short* __restrict__ A,
               const unsigned short* __restrict__ BT,
               const unsigned short* __restrict__ zp,
               const float* __restrict__ sc, const float* __restrict__ sh,
               float* __restrict__ out, int M)
{
    constexpr int K = 9 * C;
    constexpr int nsteps = K / 32;
    constexpr int NSEC = NT / 64;

    __shared__ __align__(16) unsigned short As[2][64 * 32];
    __shared__ __align__(16) unsigned short Bs[2][NT * 32];

    const int tid  = threadIdx.x;
    const int w    = tid >> 6;
    const int lane = tid & 63;
    const int l15  = lane & 15, quad = lane >> 4;

    const int GX = gridDim.x, GY = gridDim.y;
    const int nwg = GX * GY * gridDim.z;
    const int orig = blockIdx.x + GX * (blockIdx.y + GY * blockIdx.z);
    const int wk = (orig & 7) * (nwg >> 3) + (orig >> 3);
    const int by = wk % GY;
    const int t2 = wk / GY;
    const int bx = t2 % GX;
    const int bz = t2 / GX;

    BT  += (size_t)bz * 9216 * C;
    out += (size_t)bz * (size_t)M * 9216;

    const int row0 = by * 64;
    const int p0   = bx * NT;

    f32x4 acc[4][NSEC];
#pragma unroll
    for (int m = 0; m < 4; ++m)
#pragma unroll
        for (int n = 0; n < NSEC; ++n) acc[m][n] = {0.f, 0.f, 0.f, 0.f};

    const int srow = tid >> 2;
    const int scol = (((tid & 3) ^ ((srow >> 1) & 3)) << 3);

    const unsigned short* sA = A + (size_t)(row0 + srow) * K + scol;

    const unsigned short* bas[NSEC];
    unsigned vm[NSEC];
    {
        int hB[NSEC], wB[NSEC];
#pragma unroll
        for (int r = 0; r < NSEC; ++r) {
            int pB = p0 + 64 * r + srow;
            hB[r] = pB / 96; wB[r] = pB % 96;
            bas[r] = BT + (size_t)pB * C + scol;
            vm[r] = 0u;
        }
#pragma unroll
        for (int tap = 0; tap < 9; ++tap) {
            const int dh = tap / 3 - 1, dw = tap % 3 - 1;
#pragma unroll
            for (int r = 0; r < NSEC; ++r)
                vm[r] |= (unsigned)(((unsigned)(hB[r] + dh) < 96u) &&
                                    ((unsigned)(wB[r] + dw) < 96u)) << tap;
        }
    }

    int tap_s = 0, kk_s = 0;
    int offC_s = -97 * C;
    const unsigned short* sel[NSEC];
#pragma unroll
    for (int r = 0; r < NSEC; ++r)
        sel[r] = (vm[r] & 1u) ? (bas[r] + offC_s) : zp;

    auto STAGE = [&](int pb) {
        gload16(sA, &As[0][0] + pb * 2048 + w * 512);
#pragma unroll
        for (int r = 0; r < NSEC; ++r)
            gload16(sel[r], &Bs[0][0] + pb * (NT * 32) + w * 512 + r * 2048);
    };
    auto ADV = [&]() {
        sA += 32;
        kk_s += 32;
        if (kk_s == C) {
            kk_s = 0; ++tap_s;
            offC_s += ((tap_s == 3) || (tap_s == 6)) ? 94 * C : C;
#pragma unroll
            for (int r = 0; r < NSEC; ++r)
                sel[r] = ((vm[r] >> tap_s) & 1u) ? (bas[r] + offC_s) : zp;
        } else {
#pragma unroll
            for (int r = 0; r < NSEC; ++r)
                sel[r] += 32;
        }
    };

    STAGE(0);
    ADV();
    __syncthreads();

    const int swz8 = (quad ^ ((l15 >> 1) & 3)) * 8;

    auto COMPUTE = [&](auto pbc) {
        constexpr int PB = decltype(pbc)::value;
        const unsigned short* Ab = &As[0][0] + PB * 2048;
        const unsigned short* Bb = &Bs[0][0] + PB * (NT * 32);
        bf16x8 a[4], b[NSEC];
#pragma unroll
        for (int m = 0; m < 4; ++m)
            a[m] = *reinterpret_cast<const bf16x8*>(Ab + (m * 16 + l15) * 32 + swz8);
#pragma unroll
        for (int n = 0; n < NSEC; ++n)
            b[n] = *reinterpret_cast<const bf16x8*>(
                Bb + (w * (NT / 4) + n * 16 + l15) * 32 + swz8);
#pragma unroll
        for (int m = 0; m < 4; ++m)
#pragma unroll
            for (int n = 0; n < NSEC; ++n)
                acc[m][n] = __builtin_amdgcn_mfma_f32_16x16x32_bf16(
                    a[m], b[n], acc[m][n], 0, 0, 0);
    };

    for (int s = 0; s < nsteps; s += 2) {
        if (s + 1 < nsteps) { STAGE(1); ADV(); }
        COMPUTE(std::integral_constant<int, 0>{});
        __syncthreads();
        if (s + 2 < nsteps) { STAGE(0); ADV(); }
        COMPUTE(std::integral_constant<int, 1>{});
        __syncthreads();
    }

#pragma unroll
    for (int m = 0; m < 4; ++m) {
        const int co = row0 + m * 16 + quad * 4;
#pragma unroll
        for (int n = 0; n < NSEC; ++n) {
            const int pix = p0 + w * (NT / 4) + n * 16 + l15;
#pragma unroll
            for (int r = 0; r < 4; ++r) {
                const int c = co + r;
                float v = acc[m][n][r] * sc[c] + sh[c];
                out[(size_t)c * 9216 + pix] = fmaxf(v, 0.f);
            }
        }
    }
}

// ------- qk_cast: t2 rows 0..383 f32 -> qkb bf16 + rn sumsq; grid (384,B) --
__global__ __launch_bounds__(256)
void qk_cast(const float* __restrict__ t2, unsigned short* __restrict__ qkb,
             float* __restrict__ rn)
{
    const int c = blockIdx.x, b = blockIdx.y;
    const float* p = t2 + (size_t)b * 5308416 + (size_t)c * 9216;
    unsigned short* q = qkb + ((size_t)b * 384 + c) * 9216;
    float s = 0.f;
    for (int i = threadIdx.x * 4; i < 9216; i += 1024) {
        f32x4 v = *reinterpret_cast<const f32x4*>(p + i);
        s += v[0] * v[0] + v[1] * v[1] + v[2] * v[2] + v[3] * v[3];
        unsigned int u0 = (unsigned int)f2bf(v[0]) | ((unsigned int)f2bf(v[1]) << 16);
        unsigned int u1 = (unsigned int)f2bf(v[2]) | ((unsigned int)f2bf(v[3]) << 16);
        uint2 uu = {u0, u1};
        *reinterpret_cast<uint2*>(q + i) = uu;
    }
    for (int off = 32; off; off >>= 1) s += __shfl_xor(s, off, 64);
    __shared__ float red[4];
    if ((threadIdx.x & 63) == 0) red[threadIdx.x >> 6] = s;
    __syncthreads();
    if (threadIdx.x == 0)
        rn[(size_t)b * 384 + c] = red[0] + red[1] + red[2] + red[3];
}

// ------- gemm_qk: pk[b][z][c][d] = q[c] . k[d] over K-chunk 1152 -----------
// qkb bf16 [B][384][9216]; rows 0..191 q, 192..383 k. 64x64 tile, BK=32,
// 36 steps, v5 staging/swizzle/dbuf. grid (3,3,32): z = b*8+chunk.
__global__ __launch_bounds__(256)
void gemm_qk(const unsigned short* __restrict__ qkb, float* __restrict__ pk)
{
    constexpr int nsteps = 36;
    __shared__ __align__(16) unsigned short As[2][64 * 32];
    __shared__ __align__(16) unsigned short Bs[2][64 * 32];

    const int tid  = threadIdx.x;
    const int w    = tid >> 6;
    const int lane = tid & 63;
    const int l15  = lane & 15, quad = lane >> 4;

    const int c0 = blockIdx.y * 64, d0 = blockIdx.x * 64;
    const int bz = blockIdx.z, bb = bz >> 3, chunk = bz & 7;
    const int kbase = chunk * 1152;
    const unsigned short* base = qkb + (size_t)bb * 384 * 9216;

    f32x4 acc[4];
#pragma unroll
    for (int m = 0; m < 4; ++m) acc[m] = {0.f, 0.f, 0.f, 0.f};

    const int srow = tid >> 2;
    const int scol = (((tid & 3) ^ ((srow >> 1) & 3)) << 3);

    const unsigned short* sA = base + (size_t)(c0 + srow) * 9216 + kbase + scol;
    const unsigned short* sB = base + (size_t)(192 + d0 + srow) * 9216 + kbase + scol;

    auto STAGE = [&](int pb) {
        gload16(sA, &As[0][0] + pb * 2048 + w * 512);
        gload16(sB, &Bs[0][0] + pb * 2048 + w * 512);
    };
    auto ADV = [&]() { sA += 32; sB += 32; };

    STAGE(0);
    ADV();
    __syncthreads();

    const int swz8 = (quad ^ ((l15 >> 1) & 3)) * 8;

    auto COMPUTE = [&](auto pbc) {
        constexpr int PB = decltype(pbc)::value;
        const unsigned short* Ab = &As[0][0] + PB * 2048;
        const unsigned short* Bb = &Bs[0][0] + PB * 2048;
        bf16x8 a[4], b;
#pragma unroll
        for (int m = 0; m < 4; ++m)
            a[m] = *reinterpret_cast<const bf16x8*>(Ab + (m * 16 + l15) * 32 + swz8);
        b = *reinterpret_cast<const bf16x8*>(Bb + (w * 16 + l15) * 32 + swz8);
#pragma unroll
        for (int m = 0; m < 4; ++m)
            acc[m] = __builtin_amdgcn_mfma_f32_16x16x32_bf16(a[m], b, acc[m], 0, 0, 0);
    };

    for (int s = 0; s < nsteps; s += 2) {
        if (s + 1 < nsteps) { STAGE(1); ADV(); }
        COMPUTE(std::integral_constant<int, 0>{});
        __syncthreads();
        if (s + 2 < nsteps) { STAGE(0); ADV(); }
        COMPUTE(std::integral_constant<int, 1>{});
        __syncthreads();
    }

    float* dst = pk + (size_t)bz * 36864;
#pragma unroll
    for (int m = 0; m < 4; ++m) {
        const int c = c0 + m * 16 + quad * 4;
        const int d = d0 + w * 16 + l15;
#pragma unroll
        for (int r = 0; r < 4; ++r)
            dst[(size_t)(c + r) * 192 + d] = acc[m][r];
    }
}

// ------- plain GEMM: out[B][192][9216] = attn @ vT^T; NT=128, 6 steps ------
__global__ __launch_bounds__(256)
void gemm_av(const unsigned short* __restrict__ A,
             const unsigned short* __restrict__ BT,
             float* __restrict__ out)
{
    constexpr int Kd = 192, NT = 128, nsteps = 6, NSEC = 2;
    __shared__ __align__(16) unsigned short As[2][64 * 32];
    __shared__ __align__(16) unsigned short Bs[2][NT * 32];

    const int tid  = threadIdx.x;
    const int w    = tid >> 6;
    const int lane = tid & 63;
    const int l15  = lane & 15, quad = lane >> 4;

    const int GX = gridDim.x, GY = gridDim.y;
    const int nwg = GX * GY * gridDim.z;
    const int orig = blockIdx.x + GX * (blockIdx.y + GY * blockIdx.z);
    const int wk = (orig & 7) * (nwg >> 3) + (orig >> 3);
    const int by = wk % GY;
    const int t2 = wk / GY;
    const int bx = t2 % GX;
    const int bz = t2 / GX;

    A   += (size_t)bz * 36864;
    BT  += (size_t)bz * 9216 * 192;
    out += (size_t)bz * 192 * 9216;

    const int row0 = by * 64;
    const int p0   = bx * NT;

    f32x4 acc[4][NSEC];
#pragma unroll
    for (int m = 0; m < 4; ++m)
#pragma unroll
        for (int n = 0; n < NSEC; ++n) acc[m][n] = {0.f, 0.f, 0.f, 0.f};

    const int srow = tid >> 2;
    const int scol = (((tid & 3) ^ ((srow >> 1) & 3)) << 3);

    const unsigned short* sA = A + (size_t)(row0 + srow) * Kd + scol;
    const unsigned short* sB[NSEC];
#pragma unroll
    for (int r = 0; r < NSEC; ++r)
        sB[r] = BT + (size_t)(p0 + 64 * r + srow) * Kd + scol;

    auto STAGE = [&](int pb) {
        gload16(sA, &As[0][0] + pb * 2048 + w * 512);
#pragma unroll
        for (int r = 0; r < NSEC; ++r)
            gload16(sB[r], &Bs[0][0] + pb * (NT * 32) + w * 512 + r * 2048);
    };
    auto ADV = [&]() {
        sA += 32;
#pragma unroll
        for (int r = 0; r < NSEC; ++r) sB[r] += 32;
    };

    STAGE(0);
    ADV();
    __syncthreads();

    const int swz8 = (quad ^ ((l15 >> 1) & 3)) * 8;

    auto COMPUTE = [&](auto pbc) {
        constexpr int PB = decltype(pbc)::value;
        const unsigned short* Ab = &As[0][0] + PB * 2048;
        const unsigned short* Bb = &Bs[0][0] + PB * (NT * 32);
        bf16x8 a[4], b[NSEC];
#pragma unroll
        for (int m = 0; m < 4; ++m)
            a[m] = *reinterpret_cast<const bf16x8*>(Ab + (m * 16 + l15) * 32 + swz8);
#pragma unroll
        for (int n = 0; n < NSEC; ++n)
            b[n] = *reinterpret_cast<const bf16x8*>(
                Bb + (w * (NT / 4) + n * 16 + l15) * 32 + swz8);
#pragma unroll
        for (int m = 0; m < 4; ++m)
#pragma unroll
            for (int n = 0; n < NSEC; ++n)
                acc[m][n] = __builtin_amdgcn_mfma_f32_16x16x32_bf16(
                    a[m], b[n], acc[m][n], 0, 0, 0);
    };

    for (int s = 0; s < nsteps; s += 2) {
        if (s + 1 < nsteps) { STAGE(1); ADV(); }
        COMPUTE(std::integral_constant<int, 0>{});
        __syncthreads();
        if (s + 2 < nsteps) { STAGE(0); ADV(); }
        COMPUTE(std::integral_constant<int, 1>{});
        __syncthreads();
    }

#pragma unroll
    for (int m = 0; m < 4; ++m) {
        const int co = row0 + m * 16 + quad * 4;
#pragma unroll
        for (int n = 0; n < NSEC; ++n) {
            const int pix = p0 + w * (NT / 4) + n * 16 + l15;
#pragma unroll
            for (int r = 0; r < 4; ++r)
                out[(size_t)(co + r) * 9216 + pix] = acc[m][n][r];
        }
    }
}

// -------- fused reduce + norm-finalize + scale + softmax -> BF16 attn ------
__global__ __launch_bounds__(64)
void qk_softmax(const float* __restrict__ pk, const float* __restrict__ rn,
                const float* __restrict__ temp, unsigned short* __restrict__ attn)
{
    const int r = blockIdx.x, b = blockIdx.y;
    const int t = threadIdx.x;
    const float* base = pk + (size_t)b * 8 * 36864 + (size_t)r * 192;
    float e0 = 0.f, e1 = 0.f, e2 = 0.f;
#pragma unroll
    for (int z = 0; z < 8; ++z) {
        const float* q = base + (size_t)z * 36864;
        e0 += q[t]; e1 += q[t + 64]; e2 += q[t + 128];
    }
    const float* rb = rn + (size_t)b * 384;
    const float invq = 1.f / fmaxf(sqrtf(rb[r]), 1e-12f);
    const float sc = invq * temp[0];
    e0 *= sc / fmaxf(sqrtf(rb[192 + t]), 1e-12f);
    e1 *= sc / fmaxf(sqrtf(rb[192 + t + 64]), 1e-12f);
    e2 *= sc / fmaxf(sqrtf(rb[192 + t + 128]), 1e-12f);
    float m = fmaxf(e0, fmaxf(e1, e2));
    for (int off = 32; off; off >>= 1) m = fmaxf(m, __shfl_xor(m, off, 64));
    e0 = __expf(e0 - m); e1 = __expf(e1 - m); e2 = __expf(e2 - m);
    float s = e0 + e1 + e2;
    for (int off = 32; off; off >>= 1) s += __shfl_xor(s, off, 64);
    float inv = 1.f / s;
    unsigned short* p = attn + (size_t)b * 36864 + (size_t)r * 192;
    p[t]       = f2bf(e0 * inv);
    p[t + 64]  = f2bf(e1 * inv);
    p[t + 128] = f2bf(e2 * inv);
}

// ---------------- depthwise 3x3 + bias; 4 px/thread; grid (9,192,B) --------
__global__ __launch_bounds__(256)
void dwconv(const float* __restrict__ ao, const float* __restrict__ w2,
            const float* __restrict__ bias2, float* __restrict__ out)
{
    const int c = blockIdx.y;
    const int p4 = blockIdx.x * 1024 + threadIdx.x * 4;
    const int h = p4 / 96, w0 = p4 % 96;
    const float* sp = ao + (size_t)blockIdx.z * 1769472 + (size_t)c * 9216;
    float wgt[9];
#pragma unroll
    for (int i = 0; i < 9; ++i) wgt[i] = w2[c * 9 + i];
    const float bv = bias2[c];
    float a0 = bv, a1 = bv, a2 = bv, a3 = bv;

    if (h >= 1 && h <= 94 && w0 >= 4 && w0 <= 88) {
#pragma unroll
        for (int kh = 0; kh < 3; ++kh) {
            const float* rp = sp + (h + kh - 1) * 96 + w0 - 1;
            float f0 = rp[0], f1 = rp[1], f2 = rp[2];
            float f3 = rp[3], f4 = rp[4], f5 = rp[5];
            float g0 = wgt[kh * 3], g1 = wgt[kh * 3 + 1], g2 = wgt[kh * 3 + 2];
            a0 += g0 * f0 + g1 * f1 + g2 * f2;
            a1 += g0 * f1 + g1 * f2 + g2 * f3;
            a2 += g0 * f2 + g1 * f3 + g2 * f4;
            a3 += g0 * f3 + g1 * f4 + g2 * f5;
        }
    } else {
        float aa[4] = {bv, bv, bv, bv};
#pragma unroll
        for (int j = 0; j < 4; ++j) {
            const int w = w0 + j;
#pragma unroll
            for (int kh = 0; kh < 3; ++kh) {
                int hh = h + kh - 1;
                if ((unsigned)hh >= 96u) continue;
#pragma unroll
                for (int kw = 0; kw < 3; ++kw) {
                    int ww = w + kw - 1;
                    if ((unsigned)ww >= 96u) continue;
                    aa[j] += wgt[kh * 3 + kw] * sp[hh * 96 + ww];
                }
            }
        }
        a0 = aa[0]; a1 = aa[1]; a2 = aa[2]; a3 = aa[3];
    }

    f32x4 o = {a0, a1, a2, a3};
    *reinterpret_cast<f32x4*>(
        out + (size_t)blockIdx.z * 1769472 + (size_t)c * 9216 + p4) = o;
}

extern "C" void kernel_launch(void* const* d_in, const int* in_sizes, int n_in,
                              void* d_out, int out_size, void* d_ws, size_t ws_size,
                              hipStream_t stream)
{
    float* out = (float*)d_out;

    static const int expected_sizes[16] = {
        2359296, 110592, 192, 192, 192, 192, 192,
        995328, 576, 576, 576, 576, 576, 1, 1728, 192
    };
    if (n_in != 16) {
        beacon_kernel<<<1, 256, 0, stream>>>(out, 100000.f + (float)n_in);
        return;
    }
    for (int i = 0; i < 16; ++i) {
        if (in_sizes[i] != expected_sizes[i]) {
            beacon_kernel<<<1, 256, 0, stream>>>(out, 1000.f * (float)(i + 1));
            return;
        }
    }
    if (out_size != 7077888) {
        beacon_kernel<<<1, 256, 0, stream>>>(out, 50000.f);
        return;
    }
    const size_t needed = (size_t)34913536 * 4;  // 139.65 MB
    if (ws_size < needed) {
        beacon_kernel<<<1, 256, 0, stream>>>(out, 200.f + (float)(ws_size >> 20));
        return;
    }

    const float* x    = (const float*)d_in[0];
    const float* w0   = (const float*)d_in[1];
    const float* b0   = (const float*)d_in[2];
    const float* g0   = (const float*)d_in[3];
    const float* be0  = (const float*)d_in[4];
    const float* m0   = (const float*)d_in[5];
    const float* v0   = (const float*)d_in[6];
    const float* w1   = (const float*)d_in[7];
    const float* b1   = (const float*)d_in[8];
    const float* g1   = (const float*)d_in[9];
    const float* be1  = (const float*)d_in[10];
    const float* m1   = (const float*)d_in[11];
    const float* v1   = (const float*)d_in[12];
    const float* temp = (const float*)d_in[13];
    const float* w2   = (const float*)d_in[14];
    const float* bi2  = (const float*)d_in[15];

    float* ws    = (float*)d_ws;
    float* yb    = ws;                        // 4 x 1,769,472 f
    float* t2b   = ws + 7077888;              // 4 x 5,308,416 f
    unsigned short* attnb = (unsigned short*)(ws + 28311552);  // 4 x 36,864 bf16
    float* sc0   = ws + 28459008;
    float* sh0   = ws + 28459200;
    float* sc1   = ws + 28459392;
    float* sh1   = ws + 28459968;
    float* zpf   = ws + 28460544;             // 256 f zero page
    unsigned short* zp  = (unsigned short*)zpf;
    unsigned short* A0  = (unsigned short*)(ws + 28460800);  // 110,592 bf16
    unsigned short* A1  = (unsigned short*)(ws + 28516096);  // 995,328 bf16
    unsigned short* xT  = (unsigned short*)(ws + 29013760);  // 4 x 9216x64 bf16
    unsigned short* tbT = (unsigned short*)(ws + 30193408);  // 4 x 9216x192 bf16
    unsigned short* vT  = tbT;   // alias: tbT dead after conv2
    float* pk  = ws + 33732352;               // 4 x 8 x 36864 f
    float* rn  = ws + 34912000;               // 4 x 384 f raw sum-of-squares
    unsigned short* qkb = (unsigned short*)yb;  // alias: yb dead after build_tT
    float* aob = yb;  // alias: qkb dead after gemm_qk

    prep_kernel<<<dim3(4330), dim3(256), 0, stream>>>(
        w0, w1, g0, b0, be0, m0, v0, g1, b1, be1, m1, v1,
        A0, A1, sc0, sh0, sc1, sh1, zpf, rn);

    txpose_kernel<<<dim3(144, 1, 4), dim3(256), 0, stream>>>(
        x, xT, 64, (long)64 * 9216, (long)9216 * 64);
    gemm_conv<64, 128><<<dim3(72, 3, 4), dim3(256), 0, stream>>>(
        A0, xT, zp, sc0, sh0, yb, 192);
    build_tT<<<dim3(144, 3, 4), dim3(256), 0, stream>>>(yb, tbT);
    gemm_conv<192, 256><<<dim3(36, 9, 4), dim3(256), 0, stream>>>(
        A1, tbT, zp, sc1, sh1, t2b, 576);
    qk_cast<<<dim3(384, 4), dim3(256), 0, stream>>>(t2b, qkb, rn);
    gemm_qk<<<dim3(3, 3, 32), dim3(256), 0, stream>>>(qkb, pk);
    qk_softmax<<<dim3(192, 4), dim3(64), 0, stream>>>(pk, rn, temp, attnb);
    // vT overwrites tbT (dead after conv2); reads v-section of t2b
    txpose_kernel<<<dim3(144, 3, 4), dim3(256), 0, stream>>>(
        t2b + (size_t)384 * 9216, vT, 192, (long)5308416, (long)9216 * 192);
    gemm_av<<<dim3(72, 3, 4), dim3(256), 0, stream>>>(attnb, vT, aob);
    dwconv<<<dim3(9, 192, 4), dim3(256), 0, stream>>>(aob, w2, bi2, out);
}

// Round 16
// 334.645 us; speedup vs baseline: 1.4515x; 1.0711x over previous
//
#include <hip/hip_runtime.h>
#include <hip/hip_bf16.h>

// Round 29: delete the f32 t2 round-trip.
//  * gemm_conv gains BF16OUT: conv2 writes bf16 t2bb[b][576][9216] directly
//    (aliased over t2b slot). WRITE 82.9 -> 41.5 MB. Branch q/k-vs-v not
//    needed: single contiguous buffer, same [c][pix] layout.
//  * qk_cast DELETED (~85 MB traffic). gemm_qk reads t2bb rows 0..383.
//  * rownorms_bf16: 28 MB bf16 read, direct rn store (no atomics).
//  * txpose_bf16: vT from bf16 v rows (14 MB read, ushort LDS tile).
// conv1/build_tT/gemm_av/dwconv/prep = round 28. Launches 11.
// ws layout (floats), total 34,913,536 f = 139.65 MB:
//   yb/aob[0,7077888) t2bb(ush)[7077888..] attnb(ush)[28311552..28459008)
//   sc0@28459008 sh0@28459200 sc1@28459392 sh1@28459968 zp@28460544 (256 f)
//   A0 ush @f 28460800 | A1 ush @f 28516096
//   xT ush @f 29013760 | tbT/vT ush @f 30193408
//   pk [33732352, 34912000) | rn [34912000, 34913536)

typedef __hip_bfloat16 bf16;
typedef short bf16x8 __attribute__((ext_vector_type(8)));
typedef float f32x4 __attribute__((ext_vector_type(4)));

typedef const __attribute__((address_space(1))) unsigned short* gas_ptr;
typedef __attribute__((address_space(3))) unsigned short* las_ptr;

__device__ __forceinline__ void gload16(const unsigned short* g, unsigned short* l)
{
    __builtin_amdgcn_global_load_lds((gas_ptr)g, (las_ptr)l, 16, 0, 0);
}

__device__ __forceinline__ unsigned short f2bf(float v)
{
    bf16 h = __float2bfloat16(v);
    return *reinterpret_cast<unsigned short*>(&h);
}

__device__ __forceinline__ float bf2f(unsigned short u)
{
    return __uint_as_float((unsigned int)u << 16);
}

__global__ void beacon_kernel(float* out, float val)
{
    out[threadIdx.x] = val;
}

// ------- prep: weight reorders + BN fold + zero page + rn zero -------------
__global__ __launch_bounds__(256)
void prep_kernel(const float* __restrict__ w0s, const float* __restrict__ w1s,
                 const float* g0, const float* b0, const float* be0,
                 const float* m0, const float* v0,
                 const float* g1, const float* b1, const float* be1,
                 const float* m1, const float* v1,
                 unsigned short* __restrict__ A0, unsigned short* __restrict__ A1,
                 float* sc0, float* sh0, float* sc1, float* sh1,
                 float* zpf, float* rn)
{
    int i = blockIdx.x * 256 + threadIdx.x;
    if (i < 110592) {
        int o = i / 576, r = i % 576, tap = r / 64, ci = r % 64;
        A0[i] = f2bf(w0s[(size_t)o * 576 + ci * 9 + tap]);
    } else if (i < 1105920) {
        int j = i - 110592;
        int o = j / 1728, r = j % 1728, tap = r / 192, ci = r % 192;
        A1[j] = f2bf(w1s[(size_t)o * 1728 + ci * 9 + tap]);
    } else if (i < 1106112) {
        int c = i - 1105920;
        float s = g0[c] * rsqrtf(v0[c] + 1e-5f);
        sc0[c] = s;
        sh0[c] = (b0[c] - m0[c]) * s + be0[c];
    } else if (i < 1106688) {
        int c = i - 1106112;
        float s = g1[c] * rsqrtf(v1[c] + 1e-5f);
        sc1[c] = s;
        sh1[c] = (b1[c] - m1[c]) * s + be1[c];
    } else if (i < 1106944) {
        zpf[i - 1106688] = 0.f;
    } else if (i < 1108480) {
        rn[i - 1106944] = 0.f;
    }
}

// ------- transpose: src f32 [C][9216] -> dst bf16 [9216][C]; grid (144,C/64,B)
__global__ __launch_bounds__(256)
void txpose_kernel(const float* __restrict__ src, unsigned short* __restrict__ dst,
                   int C, long sbs, long dbs)
{
    __shared__ float tile[64][65];
    const int p0 = blockIdx.x * 64, c0 = blockIdx.y * 64;
    src += (size_t)blockIdx.z * sbs;
    dst += (size_t)blockIdx.z * dbs;
    for (int i = threadIdx.x; i < 4096; i += 256) {
        int r = i >> 6, c = i & 63;
        tile[c][r] = src[(size_t)(c0 + r) * 9216 + p0 + c];
    }
    __syncthreads();
    for (int i = threadIdx.x; i < 2048; i += 256) {
        int p = i >> 5, cp = (i & 31) * 2;
        unsigned int u = (unsigned int)f2bf(tile[p][cp])
                       | ((unsigned int)f2bf(tile[p][cp + 1]) << 16);
        *reinterpret_cast<unsigned int*>(dst + (size_t)(p0 + p) * C + c0 + cp) = u;
    }
}

// ------- transpose bf16: src ush [192][9216] -> dst ush [9216][192] --------
// grid (144, 3, B); sbs/dbs in ushorts.
__global__ __launch_bounds__(256)
void txpose_bf16(const unsigned short* __restrict__ src,
                 unsigned short* __restrict__ dst, long sbs, long dbs)
{
    __shared__ unsigned short tile[64][66];
    const int p0 = blockIdx.x * 64, c0 = blockIdx.y * 64;
    src += (size_t)blockIdx.z * sbs;
    dst += (size_t)blockIdx.z * dbs;
    for (int i = threadIdx.x; i < 4096; i += 256) {
        int r = i >> 6, c = i & 63;
        tile[c][r] = src[(size_t)(c0 + r) * 9216 + p0 + c];
    }
    __syncthreads();
    for (int i = threadIdx.x; i < 2048; i += 256) {
        int p = i >> 5, cp = (i & 31) * 2;
        unsigned int u = (unsigned int)tile[p][cp]
                       | ((unsigned int)tile[p][cp + 1] << 16);
        *reinterpret_cast<unsigned int*>(dst + (size_t)(p0 + p) * 192 + c0 + cp) = u;
    }
}

// ------- fused build_t + transpose -> tbT bf16 [B][9216][192]; grid (144,3,B)
__global__ __launch_bounds__(256)
void build_tT(const float* __restrict__ y, unsigned short* __restrict__ tbT)
{
    __shared__ float tile[64][65];
    const int p0 = blockIdx.x * 64, c0 = blockIdx.y * 64;
    y += (size_t)blockIdx.z * 192 * 9216;
    tbT += (size_t)blockIdx.z * 9216 * 192;
    for (int i = threadIdx.x; i < 4096; i += 256) {
        int r = i >> 6, pcol = i & 63;
        const int c = c0 + r;
        const int pix = p0 + pcol;
        const float* yp = y + (size_t)c * 9216;
        float val;
        if (c0 == 64) {
            val = yp[pix];
        } else {
            const int oh = pix / 96, ow = pix % 96;
            float fh = fminf(fmaxf(oh * 0.5f - 0.25f, 0.f), 47.f);
            float fw = fminf(fmaxf(ow * 0.5f - 0.25f, 0.f), 47.f);
            int hlo = (int)floorf(fh);
            int wlo = (int)floorf(fw);
            int hhi = (hlo < 47) ? hlo + 1 : 47;
            int whi = (wlo < 47) ? wlo + 1 : 47;
            float ff = fh - (float)hlo;
            float fg = fw - (float)wlo;
            int hs[2] = {hlo, hhi}, wss[2] = {wlo, whi};
            float p[2][2];
            for (int a = 0; a < 2; ++a)
                for (int e = 0; e < 2; ++e) {
                    const float* q = yp + (hs[a] * 2) * 96 + wss[e] * 2;
                    float v00 = q[0], v01 = q[1], v10 = q[96], v11 = q[97];
                    p[a][e] = (c0 == 0)
                        ? fmaxf(fmaxf(v00, v01), fmaxf(v10, v11))
                        : 0.25f * (v00 + v01 + v10 + v11);
                }
            val = (p[0][0] * (1.f - ff) + p[1][0] * ff) * (1.f - fg)
                + (p[0][1] * (1.f - ff) + p[1][1] * ff) * fg;
        }
        tile[pcol][r] = val;
    }
    __syncthreads();
    for (int i = threadIdx.x; i < 2048; i += 256) {
        int p = i >> 5, cp = (i & 31) * 2;
        unsigned int u = (unsigned int)f2bf(tile[p][cp])
                       | ((unsigned int)f2bf(tile[p][cp + 1]) << 16);
        *reinterpret_cast<unsigned int*>(tbT + (size_t)(p0 + p) * 192 + c0 + cp) = u;
    }
}

// ------- implicit-im2col GEMM v9 = v7 + BF16OUT epilogue -------------------
template<int C, int NT, bool BF16OUT>
__global__ __launch_bounds__(256)
void gemm_conv(const unsigned short* __restrict__ A,
               const unsigned short* __restrict__ BT,
               const unsigned short* __restrict__ zp,
               const float* __restrict__ sc, const float* __restrict__ sh,
               float* __restrict__ outf, unsigned short* __restrict__ outb,
               int M)
{
    constexpr int K = 9 * C;
    constexpr int nsteps = K / 32;
    constexpr int NSEC = NT / 64;

    __shared__ __align__(16) unsigned short As[2][64 * 32];
    __shared__ __align__(16) unsigned short Bs[2][NT * 32];

    const int tid  = threadIdx.x;
    const int w    = tid >> 6;
    const int lane = tid & 63;
    const int l15  = lane & 15, quad = lane >> 4;

    const int GX = gridDim.x, GY = gridDim.y;
    const int nwg = GX * GY * gridDim.z;
    const int orig = blockIdx.x + GX * (blockIdx.y + GY * blockIdx.z);
    const int wk = (orig & 7) * (nwg >> 3) + (orig >> 3);
    const int by = wk % GY;
    const int t2 = wk / GY;
    const int bx = t2 % GX;
    const int bz = t2 / GX;

    BT += (size_t)bz * 9216 * C;
    if constexpr (BF16OUT) outb += (size_t)bz * (size_t)M * 9216;
    else                   outf += (size_t)bz * (size_t)M * 9216;

    const int row0 = by * 64;
    const int p0   = bx * NT;

    f32x4 acc[4][NSEC];
#pragma unroll
    for (int m = 0; m < 4; ++m)
#pragma unroll
        for (int n = 0; n < NSEC; ++n) acc[m][n] = {0.f, 0.f, 0.f, 0.f};

    const int srow = tid >> 2;
    const int scol = (((tid & 3) ^ ((srow >> 1) & 3)) << 3);

    const unsigned short* sA = A + (size_t)(row0 + srow) * K + scol;

    const unsigned short* bas[NSEC];
    unsigned vm[NSEC];
    {
        int hB[NSEC], wB[NSEC];
#pragma unroll
        for (int r = 0; r < NSEC; ++r) {
            int pB = p0 + 64 * r + srow;
            hB[r] = pB / 96; wB[r] = pB % 96;
            bas[r] = BT + (size_t)pB * C + scol;
            vm[r] = 0u;
        }
#pragma unroll
        for (int tap = 0; tap < 9; ++tap) {
            const int dh = tap / 3 - 1, dw = tap % 3 - 1;
#pragma unroll
            for (int r = 0; r < NSEC; ++r)
                vm[r] |= (unsigned)(((unsigned)(hB[r] + dh) < 96u) &&
                                    ((unsigned)(wB[r] + dw) < 96u)) << tap;
        }
    }

    int tap_s = 0, kk_s = 0;
    int offC_s = -97 * C;
    const unsigned short* sel[NSEC];
#pragma unroll
    for (int r = 0; r < NSEC; ++r)
        sel[r] = (vm[r] & 1u) ? (bas[r] + offC_s) : zp;

    auto STAGE = [&](int pb) {
        gload16(sA, &As[0][0] + pb * 2048 + w * 512);
#pragma unroll
        for (int r = 0; r < NSEC; ++r)
            gload16(sel[r], &Bs[0][0] + pb * (NT * 32) + w * 512 + r * 2048);
    };
    auto ADV = [&]() {
        sA += 32;
        kk_s += 32;
        if (kk_s == C) {
            kk_s = 0; ++tap_s;
            offC_s += ((tap_s == 3) || (tap_s == 6)) ? 94 * C : C;
#pragma unroll
            for (int r = 0; r < NSEC; ++r)
                sel[r] = ((vm[r] >> tap_s) & 1u) ? (bas[r] + offC_s) : zp;
        } else {
#pragma unroll
            for (int r = 0; r < NSEC; ++r)
                sel[r] += 32;
        }
    };

    STAGE(0);
    ADV();
    __syncthreads();

    const int swz8 = (quad ^ ((l15 >> 1) & 3)) * 8;

    auto COMPUTE = [&](auto pbc) {
        constexpr int PB = decltype(pbc)::value;
        const unsigned short* Ab = &As[0][0] + PB * 2048;
        const unsigned short* Bb = &Bs[0][0] + PB * (NT * 32);
        bf16x8 a[4], b[NSEC];
#pragma unroll
        for (int m = 0; m < 4; ++m)
            a[m] = *reinterpret_cast<const bf16x8*>(Ab + (m * 16 + l15) * 32 + swz8);
#pragma unroll
        for (int n = 0; n < NSEC; ++n)
            b[n] = *reinterpret_cast<const bf16x8*>(
                Bb + (w * (NT / 4) + n * 16 + l15) * 32 + swz8);
#pragma unroll
        for (int m = 0; m < 4; ++m)
#pragma unroll
            for (int n = 0; n < NSEC; ++n)
                acc[m][n] = __builtin_amdgcn_mfma_f32_16x16x32_bf16(
                    a[m], b[n], acc[m][n], 0, 0, 0);
    };

    for (int s = 0; s < nsteps; s += 2) {
        if (s + 1 < nsteps) { STAGE(1); ADV(); }
        COMPUTE(std::integral_constant<int, 0>{});
        __syncthreads();
        if (s + 2 < nsteps) { STAGE(0); ADV(); }
        COMPUTE(std::integral_constant<int, 1>{});
        __syncthreads();
    }

#pragma unroll
    for (int m = 0; m < 4; ++m) {
        const int co = row0 + m * 16 + quad * 4;
#pragma unroll
        for (int n = 0; n < NSEC; ++n) {
            const int pix = p0 + w * (NT / 4) + n * 16 + l15;
#pragma unroll
            for (int r = 0; r < 4; ++r) {
                const int c = co + r;
                float v = fmaxf(acc[m][n][r] * sc[c] + sh[c], 0.f);
                if constexpr (BF16OUT)
                    outb[(size_t)c * 9216 + pix] = f2bf(v);
                else
                    outf[(size_t)c * 9216 + pix] = v;
            }
        }
    }
}

// ------- rownorms_bf16: rn[b][c] = sum of squares of t2bb row; grid (384,B) -
__global__ __launch_bounds__(256)
void rownorms_bf16(const unsigned short* __restrict__ t2bb, float* __restrict__ rn)
{
    const int c = blockIdx.x, b = blockIdx.y;
    const unsigned short* p = t2bb + (size_t)b * 5308416 + (size_t)c * 9216;
    float s = 0.f;
    for (int i = threadIdx.x * 8; i < 9216; i += 2048) {
        bf16x8 v = *reinterpret_cast<const bf16x8*>(p + i);
#pragma unroll
        for (int j = 0; j < 8; ++j) {
            float f = bf2f((unsigned short)v[j]);
            s += f * f;
        }
    }
    for (int off = 32; off; off >>= 1) s += __shfl_xor(s, off, 64);
    __shared__ float red[4];
    if ((threadIdx.x & 63) == 0) red[threadIdx.x >> 6] = s;
    __syncthreads();
    if (threadIdx.x == 0)
        rn[(size_t)b * 384 + c] = red[0] + red[1] + red[2] + red[3];
}

// ------- gemm_qk: pk[b][z][c][d] = q[c].k[d] over K-chunk 1152 -------------
// t2bb bf16, batch stride 5,308,416 ush; rows 0..191 q, 192..383 k.
__global__ __launch_bounds__(256)
void gemm_qk(const unsigned short* __restrict__ t2bb, float* __restrict__ pk)
{
    constexpr int nsteps = 36;
    __shared__ __align__(16) unsigned short As[2][64 * 32];
    __shared__ __align__(16) unsigned short Bs[2][64 * 32];

    const int tid  = threadIdx.x;
    const int w    = tid >> 6;
    const int lane = tid & 63;
    const int l15  = lane & 15, quad = lane >> 4;

    const int c0 = blockIdx.y * 64, d0 = blockIdx.x * 64;
    const int bz = blockIdx.z, bb = bz >> 3, chunk = bz & 7;
    const int kbase = chunk * 1152;
    const unsigned short* base = t2bb + (size_t)bb * 5308416;

    f32x4 acc[4];
#pragma unroll
    for (int m = 0; m < 4; ++m) acc[m] = {0.f, 0.f, 0.f, 0.f};

    const int srow = tid >> 2;
    const int scol = (((tid & 3) ^ ((srow >> 1) & 3)) << 3);

    const unsigned short* sA = base + (size_t)(c0 + srow) * 9216 + kbase + scol;
    const unsigned short* sB = base + (size_t)(192 + d0 + srow) * 9216 + kbase + scol;

    auto STAGE = [&](int pb) {
        gload16(sA, &As[0][0] + pb * 2048 + w * 512);
        gload16(sB, &Bs[0][0] + pb * 2048 + w * 512);
    };
    auto ADV = [&]() { sA += 32; sB += 32; };

    STAGE(0);
    ADV();
    __syncthreads();

    const int swz8 = (quad ^ ((l15 >> 1) & 3)) * 8;

    auto COMPUTE = [&](auto pbc) {
        constexpr int PB = decltype(pbc)::value;
        const unsigned short* Ab = &As[0][0] + PB * 2048;
        const unsigned short* Bb = &Bs[0][0] + PB * 2048;
        bf16x8 a[4], b;
#pragma unroll
        for (int m = 0; m < 4; ++m)
            a[m] = *reinterpret_cast<const bf16x8*>(Ab + (m * 16 + l15) * 32 + swz8);
        b = *reinterpret_cast<const bf16x8*>(Bb + (w * 16 + l15) * 32 + swz8);
#pragma unroll
        for (int m = 0; m < 4; ++m)
            acc[m] = __builtin_amdgcn_mfma_f32_16x16x32_bf16(a[m], b, acc[m], 0, 0, 0);
    };

    for (int s = 0; s < nsteps; s += 2) {
        if (s + 1 < nsteps) { STAGE(1); ADV(); }
        COMPUTE(std::integral_constant<int, 0>{});
        __syncthreads();
        if (s + 2 < nsteps) { STAGE(0); ADV(); }
        COMPUTE(std::integral_constant<int, 1>{});
        __syncthreads();
    }

    float* dst = pk + (size_t)bz * 36864;
#pragma unroll
    for (int m = 0; m < 4; ++m) {
        const int c = c0 + m * 16 + quad * 4;
        const int d = d0 + w * 16 + l15;
#pragma unroll
        for (int r = 0; r < 4; ++r)
            dst[(size_t)(c + r) * 192 + d] = acc[m][r];
    }
}

// ------- plain GEMM: out[B][192][9216] = attn @ vT^T; NT=128, 6 steps ------
__global__ __launch_bounds__(256)
void gemm_av(const unsigned short* __restrict__ A,
             const unsigned short* __restrict__ BT,
             float* __restrict__ out)
{
    constexpr int Kd = 192, NT = 128, nsteps = 6, NSEC = 2;
    __shared__ __align__(16) unsigned short As[2][64 * 32];
    __shared__ __align__(16) unsigned short Bs[2][NT * 32];

    const int tid  = threadIdx.x;
    const int w    = tid >> 6;
    const int lane = tid & 63;
    const int l15  = lane & 15, quad = lane >> 4;

    const int GX = gridDim.x, GY = gridDim.y;
    const int nwg = GX * GY * gridDim.z;
    const int orig = blockIdx.x + GX * (blockIdx.y + GY * blockIdx.z);
    const int wk = (orig & 7) * (nwg >> 3) + (orig >> 3);
    const int by = wk % GY;
    const int t2 = wk / GY;
    const int bx = t2 % GX;
    const int bz = t2 / GX;

    A   += (size_t)bz * 36864;
    BT  += (size_t)bz * 9216 * 192;
    out += (size_t)bz * 192 * 9216;

    const int row0 = by * 64;
    const int p0   = bx * NT;

    f32x4 acc[4][NSEC];
#pragma unroll
    for (int m = 0; m < 4; ++m)
#pragma unroll
        for (int n = 0; n < NSEC; ++n) acc[m][n] = {0.f, 0.f, 0.f, 0.f};

    const int srow = tid >> 2;
    const int scol = (((tid & 3) ^ ((srow >> 1) & 3)) << 3);

    const unsigned short* sA = A + (size_t)(row0 + srow) * Kd + scol;
    const unsigned short* sB[NSEC];
#pragma unroll
    for (int r = 0; r < NSEC; ++r)
        sB[r] = BT + (size_t)(p0 + 64 * r + srow) * Kd + scol;

    auto STAGE = [&](int pb) {
        gload16(sA, &As[0][0] + pb * 2048 + w * 512);
#pragma unroll
        for (int r = 0; r < NSEC; ++r)
            gload16(sB[r], &Bs[0][0] + pb * (NT * 32) + w * 512 + r * 2048);
    };
    auto ADV = [&]() {
        sA += 32;
#pragma unroll
        for (int r = 0; r < NSEC; ++r) sB[r] += 32;
    };

    STAGE(0);
    ADV();
    __syncthreads();

    const int swz8 = (quad ^ ((l15 >> 1) & 3)) * 8;

    auto COMPUTE = [&](auto pbc) {
        constexpr int PB = decltype(pbc)::value;
        const unsigned short* Ab = &As[0][0] + PB * 2048;
        const unsigned short* Bb = &Bs[0][0] + PB * (NT * 32);
        bf16x8 a[4], b[NSEC];
#pragma unroll
        for (int m = 0; m < 4; ++m)
            a[m] = *reinterpret_cast<const bf16x8*>(Ab + (m * 16 + l15) * 32 + swz8);
#pragma unroll
        for (int n = 0; n < NSEC; ++n)
            b[n] = *reinterpret_cast<const bf16x8*>(
                Bb + (w * (NT / 4) + n * 16 + l15) * 32 + swz8);
#pragma unroll
        for (int m = 0; m < 4; ++m)
#pragma unroll
            for (int n = 0; n < NSEC; ++n)
                acc[m][n] = __builtin_amdgcn_mfma_f32_16x16x32_bf16(
                    a[m], b[n], acc[m][n], 0, 0, 0);
    };

    for (int s = 0; s < nsteps; s += 2) {
        if (s + 1 < nsteps) { STAGE(1); ADV(); }
        COMPUTE(std::integral_constant<int, 0>{});
        __syncthreads();
        if (s + 2 < nsteps) { STAGE(0); ADV(); }
        COMPUTE(std::integral_constant<int, 1>{});
        __syncthreads();
    }

#pragma unroll
    for (int m = 0; m < 4; ++m) {
        const int co = row0 + m * 16 + quad * 4;
#pragma unroll
        for (int n = 0; n < NSEC; ++n) {
            const int pix = p0 + w * (NT / 4) + n * 16 + l15;
#pragma unroll
            for (int r = 0; r < 4; ++r)
                out[(size_t)(co + r) * 9216 + pix] = acc[m][n][r];
        }
    }
}

// -------- fused reduce + norm-finalize + scale + softmax -> BF16 attn ------
__global__ __launch_bounds__(64)
void qk_softmax(const float* __restrict__ pk, const float* __restrict__ rn,
                const float* __restrict__ temp, unsigned short* __restrict__ attn)
{
    const int r = blockIdx.x, b = blockIdx.y;
    const int t = threadIdx.x;
    const float* base = pk + (size_t)b * 8 * 36864 + (size_t)r * 192;
    float e0 = 0.f, e1 = 0.f, e2 = 0.f;
#pragma unroll
    for (int z = 0; z < 8; ++z) {
        const float* q = base + (size_t)z * 36864;
        e0 += q[t]; e1 += q[t + 64]; e2 += q[t + 128];
    }
    const float* rb = rn + (size_t)b * 384;
    const float invq = 1.f / fmaxf(sqrtf(rb[r]), 1e-12f);
    const float sc = invq * temp[0];
    e0 *= sc / fmaxf(sqrtf(rb[192 + t]), 1e-12f);
    e1 *= sc / fmaxf(sqrtf(rb[192 + t + 64]), 1e-12f);
    e2 *= sc / fmaxf(sqrtf(rb[192 + t + 128]), 1e-12f);
    float m = fmaxf(e0, fmaxf(e1, e2));
    for (int off = 32; off; off >>= 1) m = fmaxf(m, __shfl_xor(m, off, 64));
    e0 = __expf(e0 - m); e1 = __expf(e1 - m); e2 = __expf(e2 - m);
    float s = e0 + e1 + e2;
    for (int off = 32; off; off >>= 1) s += __shfl_xor(s, off, 64);
    float inv = 1.f / s;
    unsigned short* p = attn + (size_t)b * 36864 + (size_t)r * 192;
    p[t]       = f2bf(e0 * inv);
    p[t + 64]  = f2bf(e1 * inv);
    p[t + 128] = f2bf(e2 * inv);
}

// ---------------- depthwise 3x3 + bias; 4 px/thread; grid (9,192,B) --------
__global__ __launch_bounds__(256)
void dwconv(const float* __restrict__ ao, const float* __restrict__ w2,
            const float* __restrict__ bias2, float* __restrict__ out)
{
    const int c = blockIdx.y;
    const int p4 = blockIdx.x * 1024 + threadIdx.x * 4;
    const int h = p4 / 96, w0 = p4 % 96;
    const float* sp = ao + (size_t)blockIdx.z * 1769472 + (size_t)c * 9216;
    float wgt[9];
#pragma unroll
    for (int i = 0; i < 9; ++i) wgt[i] = w2[c * 9 + i];
    const float bv = bias2[c];
    float a0 = bv, a1 = bv, a2 = bv, a3 = bv;

    if (h >= 1 && h <= 94 && w0 >= 4 && w0 <= 88) {
#pragma unroll
        for (int kh = 0; kh < 3; ++kh) {
            const float* rp = sp + (h + kh - 1) * 96 + w0 - 1;
            float f0 = rp[0], f1 = rp[1], f2 = rp[2];
            float f3 = rp[3], f4 = rp[4], f5 = rp[5];
            float g0 = wgt[kh * 3], g1 = wgt[kh * 3 + 1], g2 = wgt[kh * 3 + 2];
            a0 += g0 * f0 + g1 * f1 + g2 * f2;
            a1 += g0 * f1 + g1 * f2 + g2 * f3;
            a2 += g0 * f2 + g1 * f3 + g2 * f4;
            a3 += g0 * f3 + g1 * f4 + g2 * f5;
        }
    } else {
        float aa[4] = {bv, bv, bv, bv};
#pragma unroll
        for (int j = 0; j < 4; ++j) {
            const int w = w0 + j;
#pragma unroll
            for (int kh = 0; kh < 3; ++kh) {
                int hh = h + kh - 1;
                if ((unsigned)hh >= 96u) continue;
#pragma unroll
                for (int kw = 0; kw < 3; ++kw) {
                    int ww = w + kw - 1;
                    if ((unsigned)ww >= 96u) continue;
                    aa[j] += wgt[kh * 3 + kw] * sp[hh * 96 + ww];
                }
            }
        }
        a0 = aa[0]; a1 = aa[1]; a2 = aa[2]; a3 = aa[3];
    }

    f32x4 o = {a0, a1, a2, a3};
    *reinterpret_cast<f32x4*>(
        out + (size_t)blockIdx.z * 1769472 + (size_t)c * 9216 + p4) = o;
}

extern "C" void kernel_launch(void* const* d_in, const int* in_sizes, int n_in,
                              void* d_out, int out_size, void* d_ws, size_t ws_size,
                              hipStream_t stream)
{
    float* out = (float*)d_out;

    static const int expected_sizes[16] = {
        2359296, 110592, 192, 192, 192, 192, 192,
        995328, 576, 576, 576, 576, 576, 1, 1728, 192
    };
    if (n_in != 16) {
        beacon_kernel<<<1, 256, 0, stream>>>(out, 100000.f + (float)n_in);
        return;
    }
    for (int i = 0; i < 16; ++i) {
        if (in_sizes[i] != expected_sizes[i]) {
            beacon_kernel<<<1, 256, 0, stream>>>(out, 1000.f * (float)(i + 1));
            return;
        }
    }
    if (out_size != 7077888) {
        beacon_kernel<<<1, 256, 0, stream>>>(out, 50000.f);
        return;
    }
    const size_t needed = (size_t)34913536 * 4;  // 139.65 MB
    if (ws_size < needed) {
        beacon_kernel<<<1, 256, 0, stream>>>(out, 200.f + (float)(ws_size >> 20));
        return;
    }

    const float* x    = (const float*)d_in[0];
    const float* w0   = (const float*)d_in[1];
    const float* b0   = (const float*)d_in[2];
    const float* g0   = (const float*)d_in[3];
    const float* be0  = (const float*)d_in[4];
    const float* m0   = (const float*)d_in[5];
    const float* v0   = (const float*)d_in[6];
    const float* w1   = (const float*)d_in[7];
    const float* b1   = (const float*)d_in[8];
    const float* g1   = (const float*)d_in[9];
    const float* be1  = (const float*)d_in[10];
    const float* m1   = (const float*)d_in[11];
    const float* v1   = (const float*)d_in[12];
    const float* temp = (const float*)d_in[13];
    const float* w2   = (const float*)d_in[14];
    const float* bi2  = (const float*)d_in[15];

    float* ws    = (float*)d_ws;
    float* yb    = ws;                        // 4 x 1,769,472 f (conv1 y; later aob)
    unsigned short* t2bb = (unsigned short*)(ws + 7077888);  // 4 x 576x9216 bf16
    unsigned short* attnb = (unsigned short*)(ws + 28311552);
    float* sc0   = ws + 28459008;
    float* sh0   = ws + 28459200;
    float* sc1   = ws + 28459392;
    float* sh1   = ws + 28459968;
    float* zpf   = ws + 28460544;             // 256 f zero page
    unsigned short* zp  = (unsigned short*)zpf;
    unsigned short* A0  = (unsigned short*)(ws + 28460800);
    unsigned short* A1  = (unsigned short*)(ws + 28516096);
    unsigned short* xT  = (unsigned short*)(ws + 29013760);
    unsigned short* tbT = (unsigned short*)(ws + 30193408);
    unsigned short* vT  = tbT;   // alias: tbT dead after conv2
    float* pk  = ws + 33732352;
    float* rn  = ws + 34912000;
    float* aob = yb;  // alias: yb dead after build_tT

    prep_kernel<<<dim3(4330), dim3(256), 0, stream>>>(
        w0, w1, g0, b0, be0, m0, v0, g1, b1, be1, m1, v1,
        A0, A1, sc0, sh0, sc1, sh1, zpf, rn);

    txpose_kernel<<<dim3(144, 1, 4), dim3(256), 0, stream>>>(
        x, xT, 64, (long)64 * 9216, (long)9216 * 64);
    gemm_conv<64, 128, false><<<dim3(72, 3, 4), dim3(256), 0, stream>>>(
        A0, xT, zp, sc0, sh0, yb, nullptr, 192);
    build_tT<<<dim3(144, 3, 4), dim3(256), 0, stream>>>(yb, tbT);
    gemm_conv<192, 256, true><<<dim3(36, 9, 4), dim3(256), 0, stream>>>(
        A1, tbT, zp, sc1, sh1, nullptr, t2bb, 576);
    rownorms_bf16<<<dim3(384, 4), dim3(256), 0, stream>>>(t2bb, rn);
    gemm_qk<<<dim3(3, 3, 32), dim3(256), 0, stream>>>(t2bb, pk);
    qk_softmax<<<dim3(192, 4), dim3(64), 0, stream>>>(pk, rn, temp, attnb);
    // vT overwrites tbT (dead after conv2); reads v rows 384..575 of t2bb
    txpose_bf16<<<dim3(144, 3, 4), dim3(256), 0, stream>>>(
        t2bb + (size_t)384 * 9216, vT, (long)5308416, (long)9216 * 192);
    gemm_av<<<dim3(72, 3, 4), dim3(256), 0, stream>>>(attnb, vT, aob);
    dwconv<<<dim3(9, 192, 4), dim3(256), 0, stream>>>(aob, w2, bi2, out);
}